// Round 17
// baseline (345.828 us; speedup 1.0000x reference)
//
#include <hip/hip_runtime.h>
#include <cstdint>
#include <cstddef>

// BiRWKV (RWKV-6 bidirectional time-mix), B=4 T=1024 C=768 H=12 D=64 LORA=64.
// Round 17: workspace overlay — mx (mixed A-buffers, dead after the mix-GEMM)
// aliased onto the SL/Pbuf region (first written by scanA, which runs later in
// stream order). This fits nch=64 (L=16) dual-dir: scanC LDS 16->8KB doubles
// its occupancy ceiling and halves the per-block serial chain. Ladder falls
// back to nch=32-overlay (== round 16 behavior) then 16. Kernels unchanged.

#define HH   12
#define DD   64
#define CC   768
#define TT   1024
#define BBB  4
#define LR   64
#define BT   (BBB*TT)
#define WSQ  (CC*CC)

typedef unsigned short u16;
typedef _Float16 f16x8 __attribute__((ext_vector_type(8)));  // 8 f16 (4 VGPRs)
typedef float f32x4 __attribute__((ext_vector_type(4)));     // MFMA accumulator

__device__ __forceinline__ u16 f2h(float f) {
    const _Float16 h = (_Float16)f;
    return __builtin_bit_cast(u16, h);
}
__device__ __forceinline__ float h2f(u16 h) {
    return (float)__builtin_bit_cast(_Float16, h);
}

// async global->LDS DMA, 16B per lane; LDS dest = wave-uniform base + lane*16.
__device__ __forceinline__ void gl_lds16(const void* g, void* l) {
    __builtin_amdgcn_global_load_lds(
        (const __attribute__((address_space(1))) void*)g,
        (__attribute__((address_space(3))) void*)l, 16, 0, 0);
}

// pad_mask dtype detect (bool bytes vs int32 vs float32).
__device__ __forceinline__ float mask_val(const void* mp, int idx) {
    const unsigned char* b = (const unsigned char*)mp;
    const int i0 = ((const int*)mp)[0];
    if (i0 == 0x3f800000) {
        return ((const float*)mp)[idx] != 0.f ? 1.f : 0.f;
    }
    if ((b[1] | b[2] | b[3]) == 0) {
        return ((const int*)mp)[idx] != 0 ? 1.f : 0.f;
    }
    return b[idx] ? 1.f : 0.f;
}

// ---------------- prepass: weight transpose-convert, x/mu convert -------------
struct TP10 { const float* src[10]; };

__global__ __launch_bounds__(256)
void transpose_conv(TP10 tj, u16* __restrict__ dst)
{
    __shared__ float sh[32][33];
    const int j = blockIdx.z;
    const float* __restrict__ src = tj.src[j];
    u16* __restrict__ d = dst + (size_t)j * WSQ;
    const int n0 = blockIdx.x << 5, k0 = blockIdx.y << 5;
    const int tx = threadIdx.x & 31, ty = threadIdx.x >> 5;
    #pragma unroll
    for (int i = 0; i < 4; ++i)
        sh[ty + (i << 3)][tx] = src[(size_t)(k0 + ty + (i << 3)) * CC + n0 + tx];
    __syncthreads();
    #pragma unroll
    for (int i = 0; i < 4; ++i)
        d[(size_t)(n0 + ty + (i << 3)) * CC + k0 + tx] =
            f2h(sh[tx][ty + (i << 3)]);
}

__global__ __launch_bounds__(256)
void convert_x(const float* __restrict__ x, u16* __restrict__ xb)
{
    const size_t off = ((size_t)blockIdx.x * 256 + threadIdx.x) * 8;
    const float4 a = *reinterpret_cast<const float4*>(x + off);
    const float4 b = *reinterpret_cast<const float4*>(x + off + 4);
    uint4 w;
    w.x = (unsigned)f2h(a.x) | ((unsigned)f2h(a.y) << 16);
    w.y = (unsigned)f2h(a.z) | ((unsigned)f2h(a.w) << 16);
    w.z = (unsigned)f2h(b.x) | ((unsigned)f2h(b.y) << 16);
    w.w = (unsigned)f2h(b.z) | ((unsigned)f2h(b.w) << 16);
    *reinterpret_cast<uint4*>(xb + off) = w;
}

__global__ __launch_bounds__(256)
void convert_mu(const float* __restrict__ mu, u16* __restrict__ muh, int n)
{
    const int i = blockIdx.x * 256 + threadIdx.x;
    if (i < n) muh[i] = f2h(mu[i]);
}

// ---------------- mix prepass: mixed fp16 A-buffers, both dirs ----------------
__global__ __launch_bounds__(256)
void mix4_kernel(const u16* __restrict__ xb, const u16* __restrict__ muh,
                 u16* __restrict__ mx, const int dbase)
{
    const int j = blockIdx.y;
    const int slot = blockIdx.z;
    const int dir = dbase + slot;
    const int idx = blockIdx.x * 256 + threadIdx.x;     // one uint4 (8 elems)
    const int s = idx / 96;                             // CC/8 = 96
    const int c = (idx - s * 96) << 3;
    const int b = s >> 10, ts = s & (TT - 1);
    const int t = dir ? (TT - 1 - ts) : ts;
    const int tp = dir ? (t + 1) : (t - 1);
    const int musel = (j == 3) ? 4 : j;

    const uint4 xa4 = *reinterpret_cast<const uint4*>(
        xb + (size_t)(b * TT + t) * CC + c);
    uint4 xp4 = make_uint4(0u, 0u, 0u, 0u);
    if (ts > 0)
        xp4 = *reinterpret_cast<const uint4*>(
            xb + (size_t)(b * TT + tp) * CC + c);
    const uint4 m4 = *reinterpret_cast<const uint4*>(
        muh + (size_t)dir * 5 * CC + musel * CC + c);

    const f16x8 xa = __builtin_bit_cast(f16x8, xa4);
    const f16x8 xp = __builtin_bit_cast(f16x8, xp4);
    const f16x8 mm = __builtin_bit_cast(f16x8, m4);
    const f16x8 res = (xp - xa) * mm + xa;              // v_pk_* fp16

    u16* __restrict__ dst = mx + (size_t)((slot << 2) + j) * ((size_t)BT * CC);
    *reinterpret_cast<uint4*>(dst + (size_t)s * CC + c) =
        __builtin_bit_cast(uint4, res);
}

// ---------------- fp16 MFMA GEMM: 128x128 tile, 4 waves, gl_lds staging -------
struct GB { const u16* Wt[8]; const u16* Ab[8]; float* out[8];
            const float* mu[8]; int act[8]; int dirv[8]; };

__global__ __launch_bounds__(256)
void gemm_mfma_big(GB p, const u16* __restrict__ xb,
                   const int K, const int N, const int mixA)
{
    const int j = blockIdx.z;
    const u16* __restrict__ Wt = p.Wt[j];
    const u16* __restrict__ Ab = p.Ab[j];
    float* __restrict__ out = p.out[j];
    const float* __restrict__ mu = p.mu[j];
    const int act = p.act[j];
    const int dir = p.dirv[j];

    __shared__ __align__(16) u16 Als[128][64];
    __shared__ __align__(16) u16 Bls[128][64];
    const int tid = threadIdx.x;
    const int rowbase = blockIdx.x << 7;
    const int colbase = blockIdx.y << 7;
    const int lane = tid & 63;
    const int wid = tid >> 6;           // 0..3
    const int wr = (wid >> 1) << 6;     // 0 / 64
    const int wc = (wid & 1) << 6;      // 0 / 64
    const int lm = lane & 15;

    const int lrow = lane >> 3;
    const int gcol = (((lane & 7) ^ lrow) << 3);

    f32x4 acc[4][4] = {};

    for (int k0 = 0; k0 < K; k0 += 64) {
        if (mixA) {
            #pragma unroll
            for (int it = 0; it < 4; ++it) {
                const int c   = tid + (it << 8);
                const int row = c >> 3;
                const int ch  = c & 7;
                const int kq  = (ch ^ (row & 7)) << 3;
                *reinterpret_cast<uint4*>(&Bls[row][ch << 3]) =
                    *reinterpret_cast<const uint4*>(
                        Wt + (size_t)(colbase + row) * K + k0 + kq);
                const int s  = rowbase + row;
                const int bb = s >> 10, ts = s & (TT - 1);
                const int t  = dir ? (TT - 1 - ts) : ts;
                const int tp = dir ? (t + 1) : (t - 1);
                const uint4 xa4 = *reinterpret_cast<const uint4*>(
                    xb + (size_t)(bb * TT + t) * CC + k0 + kq);
                uint4 xp4 = make_uint4(0u, 0u, 0u, 0u);
                if (ts > 0)
                    xp4 = *reinterpret_cast<const uint4*>(
                        xb + (size_t)(bb * TT + tp) * CC + k0 + kq);
                const u16* as = reinterpret_cast<const u16*>(&xa4);
                const u16* ps = reinterpret_cast<const u16*>(&xp4);
                const float4 m0 = *reinterpret_cast<const float4*>(mu + k0 + kq);
                const float4 m1 = *reinterpret_cast<const float4*>(mu + k0 + kq + 4);
                const float mm[8] = {m0.x, m0.y, m0.z, m0.w,
                                     m1.x, m1.y, m1.z, m1.w};
                uint4 w;
                unsigned rr[4];
                #pragma unroll
                for (int q = 0; q < 4; ++q) {
                    const float a0 = h2f(as[2 * q]);
                    const float a1 = h2f(as[2 * q + 1]);
                    const float p0 = h2f(ps[2 * q]);
                    const float p1 = h2f(ps[2 * q + 1]);
                    const float v0 = fmaf(p0 - a0, mm[2 * q], a0);
                    const float v1 = fmaf(p1 - a1, mm[2 * q + 1], a1);
                    rr[q] = (unsigned)f2h(v0) | ((unsigned)f2h(v1) << 16);
                }
                w.x = rr[0]; w.y = rr[1]; w.z = rr[2]; w.w = rr[3];
                *reinterpret_cast<uint4*>(&Als[row][ch << 3]) = w;
            }
        } else {
            #pragma unroll
            for (int i = 0; i < 4; ++i) {
                const int rb  = (wid << 5) + (i << 3);    // 8 rows / instr
                const int row = rb + lrow;
                gl_lds16(Ab + (size_t)(rowbase + row) * K + k0 + gcol,
                         &Als[rb][0]);
                gl_lds16(Wt + (size_t)(colbase + row) * K + k0 + gcol,
                         &Bls[rb][0]);
            }
        }
        __syncthreads();   // drains vmcnt(0): gl_lds data landed
        #pragma unroll
        for (int ks = 0; ks < 2; ++ks) {
            const int gc = (ks << 2) + (lane >> 4);       // global chunk
            const int sl = (gc ^ (lm & 7)) << 3;          // swizzled col
            f16x8 av[4], bv[4];
            #pragma unroll
            for (int mi = 0; mi < 4; ++mi)
                av[mi] = *reinterpret_cast<const f16x8*>(
                    &Als[wr + mi * 16 + lm][sl]);
            #pragma unroll
            for (int ni = 0; ni < 4; ++ni)
                bv[ni] = *reinterpret_cast<const f16x8*>(
                    &Bls[wc + ni * 16 + lm][sl]);
            #pragma unroll
            for (int mi = 0; mi < 4; ++mi)
                #pragma unroll
                for (int ni = 0; ni < 4; ++ni)
                    acc[mi][ni] = __builtin_amdgcn_mfma_f32_16x16x32_f16(
                        av[mi], bv[ni], acc[mi][ni], 0, 0, 0);
        }
        __syncthreads();
    }

    #pragma unroll
    for (int mi = 0; mi < 4; ++mi) {
        #pragma unroll
        for (int r = 0; r < 4; ++r) {
            const int srow = rowbase + wr + mi * 16 + ((lane >> 4) << 2) + r;
            if (act <= 1) {
                #pragma unroll
                for (int ni = 0; ni < 4; ++ni) {
                    float v = acc[mi][ni][r];
                    if (act == 1) v = v / (1.f + expf(-v));
                    out[(size_t)srow * N + colbase + wc + ni * 16 + lm] = v;
                }
            } else {   // act==4: store at original time order
                const int b2  = srow >> 10;
                const int ts2 = srow & (TT - 1);
                const int t2  = dir ? (TT - 1 - ts2) : ts2;
                float* op = out + (size_t)(b2 * TT + t2) * CC + colbase + wc + lm;
                #pragma unroll
                for (int ni = 0; ni < 4; ++ni)
                    op[ni * 16] = acc[mi][ni][r];
            }
        }
    }
}

// ---------------- combine: out = (fwd + bwd) * mask ----------------
__global__ __launch_bounds__(256)
void combine_kernel(float* __restrict__ out, const float* __restrict__ obuf,
                    const void* __restrict__ mask)
{
    const size_t idx = ((size_t)blockIdx.x * 256 + threadIdx.x) * 4;
    const int row = (int)(idx / CC);
    const float mv = mask_val(mask, row);
    const float4 a = *reinterpret_cast<const float4*>(out + idx);
    const float4 b = *reinterpret_cast<const float4*>(obuf + idx);
    *reinterpret_cast<float4*>(out + idx) = make_float4(
        (a.x + b.x) * mv, (a.y + b.y) * mv, (a.z + b.z) * mv, (a.w + b.w) * mv);
}

// ---------------- fp32 lora1 (x-mix @ dw1, tanh), 16-row tiles ----------------
__global__ __launch_bounds__(256)
void lora1_kernel(const float* __restrict__ x, const float* __restrict__ mu,
                  const float* __restrict__ dw1, float* __restrict__ out,
                  const int dbase)
{
    __shared__ float As[16][68];
    __shared__ float Bs[64][68];
    const int tid = threadIdx.x;
    const int rowbase = blockIdx.x << 4;
    const int slot = blockIdx.y;
    const int dir = dbase + slot;
    const float* __restrict__ muD = mu + (size_t)dir * 5 * CC + 3 * CC;
    const float* __restrict__ dw1p = dw1 + (size_t)dir * CC * LR;
    float* __restrict__ outp = out + (size_t)slot * BT * LR;

    const int arow = tid >> 4;
    const int akq  = (tid & 15) << 2;
    const int s  = rowbase + arow;
    const int bb = s >> 10, ts = s & (TT - 1);
    const int t  = dir ? (TT - 1 - ts) : ts;
    const int tp = dir ? (t + 1) : (t - 1);

    const int c0 = tid & 63;
    const int r4 = tid >> 6;

    float acc[4] = {0.f, 0.f, 0.f, 0.f};

    for (int k0 = 0; k0 < CC; k0 += 64) {
        {
            const int c = k0 + akq;
            const float4 xa = *reinterpret_cast<const float4*>(
                x + (size_t)(bb * TT + t) * CC + c);
            float4 xp = make_float4(0.f, 0.f, 0.f, 0.f);
            if (ts > 0)
                xp = *reinterpret_cast<const float4*>(
                    x + (size_t)(bb * TT + tp) * CC + c);
            const float4 m4 = *reinterpret_cast<const float4*>(muD + c);
            float4 va;
            va.x = fmaf(xp.x - xa.x, m4.x, xa.x);
            va.y = fmaf(xp.y - xa.y, m4.y, xa.y);
            va.z = fmaf(xp.z - xa.z, m4.z, xa.z);
            va.w = fmaf(xp.w - xa.w, m4.w, xa.w);
            *reinterpret_cast<float4*>(&As[arow][akq]) = va;
        }
        #pragma unroll
        for (int it = 0; it < 4; ++it) {
            const int c2 = tid + (it << 8);
            const int brow = c2 >> 4, bcol = (c2 & 15) << 2;
            *reinterpret_cast<float4*>(&Bs[brow][bcol]) =
                *reinterpret_cast<const float4*>(
                    dw1p + (size_t)(k0 + brow) * LR + bcol);
        }
        __syncthreads();
        #pragma unroll
        for (int k4 = 0; k4 < 16; ++k4) {
            float bv[4];
            #pragma unroll
            for (int q = 0; q < 4; ++q) bv[q] = Bs[(k4 << 2) + q][c0];
            #pragma unroll
            for (int i = 0; i < 4; ++i) {
                const float4 a4 = *reinterpret_cast<const float4*>(
                    &As[r4 + (i << 2)][k4 << 2]);
                acc[i] = fmaf(a4.x, bv[0], acc[i]);
                acc[i] = fmaf(a4.y, bv[1], acc[i]);
                acc[i] = fmaf(a4.z, bv[2], acc[i]);
                acc[i] = fmaf(a4.w, bv[3], acc[i]);
            }
        }
        __syncthreads();
    }
    #pragma unroll
    for (int i = 0; i < 4; ++i)
        outp[(size_t)(rowbase + r4 + (i << 2)) * LR + c0] = tanhf(acc[i]);
}

// ---------------- fp32 GEMM (lora2: decay exp(-exp)), both dirs ---------------
__global__ __launch_bounds__(256)
void gemm_kernel(const float* __restrict__ lora, const float* __restrict__ dw2,
                 const float* __restrict__ wbias, float* __restrict__ wwbuf,
                 const int dbase)
{
    __shared__ float As[16][68];
    __shared__ float Bs[16][68];
    const int tid = threadIdx.x;
    const int rowbase = blockIdx.x << 6;
    const int colbase = blockIdx.y << 6;
    const int slot = blockIdx.z;
    const int dir = dbase + slot;
    const float* __restrict__ Ap = lora + (size_t)slot * BT * LR;
    const float* __restrict__ W  = dw2 + (size_t)dir * LR * CC;
    const float* __restrict__ bias = wbias + (size_t)dir * CC;
    float* __restrict__ out = wwbuf + (size_t)slot * BT * CC;

    const int ty = tid >> 4, tx = tid & 15;
    const int am = tid >> 2;
    const int aq = tid & 3;
    const int s  = rowbase + am;
    const int bk = tid >> 4;
    const int bn = (tid & 15) << 2;

    float acc[4][4];
    #pragma unroll
    for (int i = 0; i < 4; ++i)
        #pragma unroll
        for (int j = 0; j < 4; ++j) acc[i][j] = 0.f;

    for (int k0 = 0; k0 < LR; k0 += 16) {
        const float4 va = *reinterpret_cast<const float4*>(
            Ap + (size_t)s * LR + k0 + (aq << 2));
        const float4 vb = *reinterpret_cast<const float4*>(
            W + (size_t)(k0 + bk) * CC + colbase + bn);
        As[(aq << 2) + 0][am] = va.x;
        As[(aq << 2) + 1][am] = va.y;
        As[(aq << 2) + 2][am] = va.z;
        As[(aq << 2) + 3][am] = va.w;
        *reinterpret_cast<float4*>(&Bs[bk][bn]) = vb;
        __syncthreads();
        #pragma unroll
        for (int kk = 0; kk < 16; ++kk) {
            const float4 a  = *reinterpret_cast<const float4*>(&As[kk][ty << 2]);
            const float4 bv = *reinterpret_cast<const float4*>(&Bs[kk][tx << 2]);
            const float av[4]  = {a.x, a.y, a.z, a.w};
            const float bvv[4] = {bv.x, bv.y, bv.z, bv.w};
            #pragma unroll
            for (int i = 0; i < 4; ++i)
                #pragma unroll
                for (int j = 0; j < 4; ++j)
                    acc[i][j] = fmaf(av[i], bvv[j], acc[i][j]);
        }
        __syncthreads();
    }

    #pragma unroll
    for (int i = 0; i < 4; ++i) {
        const int srow = rowbase + (ty << 2) + i;
        const int ncol = colbase + (tx << 2);
        float v[4];
        #pragma unroll
        for (int j = 0; j < 4; ++j)
            v[j] = expf(-expf(acc[i][j] + bias[ncol + j]));
        *reinterpret_cast<float4*>(out + (size_t)srow * CC + ncol) =
            make_float4(v[0], v[1], v[2], v[3]);
    }
}

// ---------------- chunked scan (A/B/C), dir-slot aware ----------------
template<int L>
__global__ __launch_bounds__(64)
void scanA_kernel(const float* __restrict__ kbuf, const float* __restrict__ vbuf,
                  const float* __restrict__ wbuf,
                  float* __restrict__ SL, float* __restrict__ Pbuf)
{
    constexpr int NCHL = TT / L;
    constexpr size_t SLN = (size_t)NCHL * BBB * HH * DD * DD;
    constexpr size_t PN  = (size_t)NCHL * BBB * HH * DD;
    __shared__ float lk[L * DD], lw[L * DD], lv[L * DD];
    const int c = blockIdx.x, h = blockIdx.y;
    const int b = blockIdx.z & (BBB - 1);
    const int slot = blockIdx.z >> 2;
    const size_t boff = (size_t)slot * BT * CC;
    const int e = threadIdx.x;
    const int rowq = e >> 4;
    const int col  = (e & 15) << 2;

    const size_t gbase = boff + (size_t)(b * TT + c * L) * CC + h * DD;
    #pragma unroll
    for (int r4 = 0; r4 < L / 4; ++r4) {
        const int row = (r4 << 2) + rowq;
        const size_t ga = gbase + (size_t)row * CC + col;
        *reinterpret_cast<float4*>(&lk[row * DD + col]) =
            *reinterpret_cast<const float4*>(kbuf + ga);
        *reinterpret_cast<float4*>(&lw[row * DD + col]) =
            *reinterpret_cast<const float4*>(wbuf + ga);
        *reinterpret_cast<float4*>(&lv[row * DD + col]) =
            *reinterpret_cast<const float4*>(vbuf + ga);
    }
    __syncthreads();

    float S[DD];
    #pragma unroll
    for (int d = 0; d < DD; ++d) S[d] = 0.f;
    float P = 1.f;

    for (int t = 0; t < L; ++t) {
        const float ve = lv[t * DD + e];
        P *= lw[t * DD + e];
        #pragma unroll
        for (int d4 = 0; d4 < 16; ++d4) {
            const float4 k4 = *reinterpret_cast<const float4*>(&lk[t * DD + (d4 << 2)]);
            const float4 w4 = *reinterpret_cast<const float4*>(&lw[t * DD + (d4 << 2)]);
            S[(d4 << 2) + 0] = fmaf(w4.x, S[(d4 << 2) + 0], k4.x * ve);
            S[(d4 << 2) + 1] = fmaf(w4.y, S[(d4 << 2) + 1], k4.y * ve);
            S[(d4 << 2) + 2] = fmaf(w4.z, S[(d4 << 2) + 2], k4.z * ve);
            S[(d4 << 2) + 3] = fmaf(w4.w, S[(d4 << 2) + 3], k4.w * ve);
        }
    }

    float* slotp = SL + (size_t)slot * SLN
                 + (size_t)((c * BBB + b) * HH + h) * DD * DD;
    #pragma unroll
    for (int d = 0; d < DD; ++d) slotp[d * DD + e] = S[d];
    Pbuf[(size_t)slot * PN + (size_t)((c * BBB + b) * HH + h) * DD + e] = P;
}

// Pass B: sequential over chunks, depth-1 register prefetch.
__global__ __launch_bounds__(64)
void scanB_kernel(float* __restrict__ SL, const float* __restrict__ Pbuf,
                  const int nch)
{
    const int h = blockIdx.x, b = blockIdx.y;
    const int dg = blockIdx.z & 3;
    const int slot = blockIdx.z >> 2;
    const size_t SLN = (size_t)nch * BBB * HH * DD * DD;
    const size_t PN  = (size_t)nch * BBB * HH * DD;
    float* __restrict__ SLs = SL + (size_t)slot * SLN;
    const float* __restrict__ Ps = Pbuf + (size_t)slot * PN;
    const int e = threadIdx.x;
    const size_t doff = (size_t)dg * 16 * DD;

    float S[16];
    #pragma unroll
    for (int i = 0; i < 16; ++i) S[i] = 0.f;

    float sl[16], pp[16];
    {
        const float* s0 = SLs + (size_t)(b * HH + h) * DD * DD + doff;
        const float* p0 = Ps + (size_t)(b * HH + h) * DD + dg * 16;
        #pragma unroll
        for (int i = 0; i < 16; ++i) { sl[i] = s0[i * DD + e]; pp[i] = p0[i]; }
    }
    for (int c = 0; c < nch; ++c) {
        float sl2[16], pp2[16];
        if (c + 1 < nch) {
            const float* s1 = SLs + (size_t)(((c + 1) * BBB + b) * HH + h) * DD * DD + doff;
            const float* p1 = Ps + (size_t)(((c + 1) * BBB + b) * HH + h) * DD + dg * 16;
            #pragma unroll
            for (int i = 0; i < 16; ++i) { sl2[i] = s1[i * DD + e]; pp2[i] = p1[i]; }
        }
        float* sc = SLs + (size_t)((c * BBB + b) * HH + h) * DD * DD + doff;
        #pragma unroll
        for (int i = 0; i < 16; ++i) {
            S[i] = fmaf(pp[i], S[i], sl[i]);
            sc[i * DD + e] = S[i];
        }
        #pragma unroll
        for (int i = 0; i < 16; ++i) { sl[i] = sl2[i]; pp[i] = pp2[i]; }
    }
}

// Pass C: in-loop coef+GroupNorm shfl; r/k packed fp16 in one LDS array.
template<int L>
__global__ __launch_bounds__(64)
void scanC_kernel(const float* __restrict__ rbuf, const float* __restrict__ kbuf,
                  const float* __restrict__ vbuf, const float* __restrict__ wbuf,
                  const float* __restrict__ gbuf, const float* __restrict__ SL,
                  const float* __restrict__ u, const float* __restrict__ lnw,
                  const float* __restrict__ lnb, u16* __restrict__ zb,
                  const int dbase)
{
    constexpr int NCHL = TT / L;
    constexpr size_t SLN = (size_t)NCHL * BBB * HH * DD * DD;
    __shared__ unsigned lrk[L * DD];            // lo = r fp16, hi = k fp16
    __shared__ float lw[L * DD];

    const int c = blockIdx.x, h = blockIdx.y;
    const int b = blockIdx.z & (BBB - 1);
    const int slot = blockIdx.z >> 2;
    const int dir = dbase + slot;
    const size_t boff = (size_t)slot * BT * CC;
    const int e = threadIdx.x;
    const int rowq = e >> 4;
    const int col  = (e & 15) << 2;

    const size_t gbase = boff + (size_t)(b * TT + c * L) * CC + h * DD;
    #pragma unroll
    for (int r4 = 0; r4 < L / 4; ++r4) {
        const int row = (r4 << 2) + rowq;
        const size_t ga = gbase + (size_t)row * CC + col;
        const float4 rv = *reinterpret_cast<const float4*>(rbuf + ga);
        const float4 kv = *reinterpret_cast<const float4*>(kbuf + ga);
        const float4 wv = *reinterpret_cast<const float4*>(wbuf + ga);
        *reinterpret_cast<float4*>(&lw[row * DD + col]) = wv;
        uint4 pk;
        pk.x = (unsigned)f2h(rv.x) | ((unsigned)f2h(kv.x) << 16);
        pk.y = (unsigned)f2h(rv.y) | ((unsigned)f2h(kv.y) << 16);
        pk.z = (unsigned)f2h(rv.z) | ((unsigned)f2h(kv.z) << 16);
        pk.w = (unsigned)f2h(rv.w) | ((unsigned)f2h(kv.w) << 16);
        *reinterpret_cast<uint4*>(&lrk[row * DD + col]) = pk;
    }
    __syncthreads();

    const float ue = u[(size_t)(dir * HH + h) * DD + e];
    const float gw = lnw[dir * CC + h * DD + e];
    const float gb = lnb[dir * CC + h * DD + e];

    float S[DD];
    if (c == 0) {
        #pragma unroll
        for (int d = 0; d < DD; ++d) S[d] = 0.f;
    } else {
        const float* slotp = SL + (size_t)slot * SLN
                           + (size_t)(((c - 1) * BBB + b) * HH + h) * DD * DD;
        #pragma unroll
        for (int d = 0; d < DD; ++d) S[d] = slotp[d * DD + e];
    }

    float ve = vbuf[gbase + e];
    float ge = gbuf[gbase + e];
    for (int t = 0; t < L; ++t) {
        float ve2 = 0.f, ge2 = 0.f;
        if (t + 1 < L) {
            ve2 = vbuf[gbase + (size_t)(t + 1) * CC + e];
            ge2 = gbuf[gbase + (size_t)(t + 1) * CC + e];
        }
        const unsigned rke = lrk[t * DD + e];
        float coef = h2f((u16)(rke & 0xffffu)) * ue * h2f((u16)(rke >> 16));
        #pragma unroll
        for (int off = 32; off > 0; off >>= 1) coef += __shfl_xor(coef, off);

        float y0 = 0.f, y1 = 0.f, y2 = 0.f, y3 = 0.f;
        #pragma unroll
        for (int d4 = 0; d4 < 16; ++d4) {
            const uint4 rk4 = *reinterpret_cast<const uint4*>(
                &lrk[t * DD + (d4 << 2)]);
            const float4 w4 = *reinterpret_cast<const float4*>(
                &lw[t * DD + (d4 << 2)]);
            const float r0 = h2f((u16)(rk4.x & 0xffffu)), k0 = h2f((u16)(rk4.x >> 16));
            const float r1 = h2f((u16)(rk4.y & 0xffffu)), k1 = h2f((u16)(rk4.y >> 16));
            const float r2 = h2f((u16)(rk4.z & 0xffffu)), k2 = h2f((u16)(rk4.z >> 16));
            const float r3 = h2f((u16)(rk4.w & 0xffffu)), k3 = h2f((u16)(rk4.w >> 16));
            y0 = fmaf(r0, S[(d4 << 2) + 0], y0);
            y1 = fmaf(r1, S[(d4 << 2) + 1], y1);
            y2 = fmaf(r2, S[(d4 << 2) + 2], y2);
            y3 = fmaf(r3, S[(d4 << 2) + 3], y3);
            S[(d4 << 2) + 0] = fmaf(w4.x, S[(d4 << 2) + 0], k0 * ve);
            S[(d4 << 2) + 1] = fmaf(w4.y, S[(d4 << 2) + 1], k1 * ve);
            S[(d4 << 2) + 2] = fmaf(w4.z, S[(d4 << 2) + 2], k2 * ve);
            S[(d4 << 2) + 3] = fmaf(w4.w, S[(d4 << 2) + 3], k3 * ve);
        }
        float y = ((y0 + y1) + (y2 + y3)) + coef * ve;

        float sum = y, sq = y * y;
        #pragma unroll
        for (int off = 32; off > 0; off >>= 1) {
            sum += __shfl_xor(sum, off);
            sq  += __shfl_xor(sq, off);
        }
        const float mean = sum * (1.f / 64.f);
        const float var  = fmaf(-mean, mean, sq * (1.f / 64.f));
        const float yn   = (y - mean) * rsqrtf(var + 1e-5f) * gw + gb;
        zb[gbase + (size_t)t * CC + e] = f2h(yn * ge);
        ve = ve2;
        ge = ge2;
    }
}

extern "C" void kernel_launch(void* const* d_in, const int* in_sizes, int n_in,
                              void* d_out, int out_size, void* d_ws, size_t ws_size,
                              hipStream_t stream)
{
    const float* x     = (const float*)d_in[0];
    const void*  mask  = d_in[1];
    const float* mu    = (const float*)d_in[2];
    const float* wbias = (const float*)d_in[3];
    const float* dw1   = (const float*)d_in[4];
    const float* dw2   = (const float*)d_in[5];
    const float* u     = (const float*)d_in[6];
    const float* Wr    = (const float*)d_in[7];
    const float* Wk    = (const float*)d_in[8];
    const float* Wv    = (const float*)d_in[9];
    const float* Wg    = (const float*)d_in[10];
    const float* Wo    = (const float*)d_in[11];
    const float* lnw   = (const float*)d_in[12];
    const float* lnb   = (const float*)d_in[13];
    float* out = (float*)d_out;

    float* ws = (float*)d_ws;
    const size_t NBT = (size_t)BT * CC;
    const size_t MUN = 2 * 5 * CC;

    // bytes needed; mx aliases the SL/Pbuf region when it fits there (mx is
    // dead once the mix-GEMM has read it; scanA writes SL strictly later).
    auto plan = [&](int nd, int nch, bool mb, bool& alias) -> size_t {
        const size_t SLN = (size_t)nch * BBB * HH * DD * DD;
        const size_t PN  = (size_t)nch * BBB * HH * DD;
        const size_t slp = (size_t)nd * (SLN + PN) * 4;          // bytes
        const size_t mxb = mb ? (size_t)4 * nd * NBT * 2 : 0;    // bytes
        alias = mb && slp >= mxb;
        return ((size_t)5 * nd * NBT + (size_t)nd * BT * LR) * 4
             + slp
             + ((size_t)nd * NBT + NBT + (size_t)10 * WSQ + MUN) * 2
             + (alias ? 0 : mxb);
    };
    int nd = 1, nch = 16; bool mixbuf = false, alias = false;
    {
        bool a;
        if      (plan(2, 64, true, a) <= ws_size) { nd = 2; nch = 64; mixbuf = true; alias = a; }
        else if (plan(2, 32, true, a) <= ws_size) { nd = 2; nch = 32; mixbuf = true; alias = a; }
        else if (plan(2, 16, true, a) <= ws_size) { nd = 2; nch = 16; mixbuf = true; alias = a; }
        else {
            nd = 1;
            mixbuf = plan(1, 16, true, a) <= ws_size;
            if (mixbuf) alias = a;
            nch = (plan(1, 64, mixbuf, a) <= ws_size) ? 64
                : (plan(1, 32, mixbuf, a) <= ws_size) ? 32 : 16;
            bool a2; (void)plan(1, nch, mixbuf, a2); alias = mixbuf && a2;
        }
    }
    const size_t SLN = (size_t)nch * BBB * HH * DD * DD;
    const size_t PN  = (size_t)nch * BBB * HH * DD;

    float* rbuf  = ws;                          // nd*NBT
    float* kbuf  = rbuf  + (size_t)nd * NBT;
    float* vbuf  = kbuf  + (size_t)nd * NBT;
    float* wwbuf = vbuf  + (size_t)nd * NBT;
    float* gbuf  = wwbuf + (size_t)nd * NBT;
    float* lora  = gbuf  + (size_t)nd * NBT;    // nd*BT*LR
    float* SL    = lora  + (size_t)nd * BT * LR;
    float* Pbuf  = SL    + (size_t)nd * SLN;
    u16*   zb    = (u16*)(Pbuf + (size_t)nd * PN);   // nd*NBT
    u16*   xbb   = zb + (size_t)nd * NBT;
    u16*   wtb   = xbb + NBT;
    u16*   muh   = wtb + (size_t)10 * WSQ;
    u16*   mx    = alias ? (u16*)SL : (muh + MUN);
    float* obuf  = rbuf;                        // free after scanC

    TP10 tj;
    const float* Wlist[5] = {Wr, Wk, Wv, Wg, Wo};
    for (int dir = 0; dir < 2; ++dir)
        for (int i = 0; i < 5; ++i)
            tj.src[dir * 5 + i] = Wlist[i] + (size_t)dir * WSQ;
    transpose_conv<<<dim3(24, 24, 10), 256, 0, stream>>>(tj, wtb);
    convert_x<<<dim3((int)(NBT / (8 * 256))), 256, 0, stream>>>(x, xbb);
    convert_mu<<<dim3((int)((MUN + 255) / 256)), 256, 0, stream>>>(mu, muh, (int)MUN);

    auto launch_scans = [&](int ndl, int dbase) {
        if (nch == 64) {
            scanA_kernel<16><<<dim3(64, HH, BBB * ndl), dim3(64), 0, stream>>>(
                kbuf, vbuf, wwbuf, SL, Pbuf);
            scanB_kernel<<<dim3(HH, BBB, 4 * ndl), dim3(64), 0, stream>>>(SL, Pbuf, 64);
            scanC_kernel<16><<<dim3(64, HH, BBB * ndl), dim3(64), 0, stream>>>(
                rbuf, kbuf, vbuf, wwbuf, gbuf, SL, u, lnw, lnb, zb, dbase);
        } else if (nch == 32) {
            scanA_kernel<32><<<dim3(32, HH, BBB * ndl), dim3(64), 0, stream>>>(
                kbuf, vbuf, wwbuf, SL, Pbuf);
            scanB_kernel<<<dim3(HH, BBB, 4 * ndl), dim3(64), 0, stream>>>(SL, Pbuf, 32);
            scanC_kernel<32><<<dim3(32, HH, BBB * ndl), dim3(64), 0, stream>>>(
                rbuf, kbuf, vbuf, wwbuf, gbuf, SL, u, lnw, lnb, zb, dbase);
        } else {
            scanA_kernel<64><<<dim3(16, HH, BBB * ndl), dim3(64), 0, stream>>>(
                kbuf, vbuf, wwbuf, SL, Pbuf);
            scanB_kernel<<<dim3(HH, BBB, 4 * ndl), dim3(64), 0, stream>>>(SL, Pbuf, 16);
            scanC_kernel<64><<<dim3(16, HH, BBB * ndl), dim3(64), 0, stream>>>(
                rbuf, kbuf, vbuf, wwbuf, gbuf, SL, u, lnw, lnb, zb, dbase);
        }
    };

    if (nd == 2) {
        // ---------- dual-direction fused path ----------
        mix4_kernel<<<dim3((int)(NBT / (8 * 256)), 4, 2), 256, 0, stream>>>(
            xbb, muh, mx, 0);

        GB pb;
        float* outs[4] = {rbuf, kbuf, vbuf, gbuf};
        for (int s = 0; s < 2; ++s) {
            const u16* wt = wtb + (size_t)s * 5 * WSQ;
            for (int j = 0; j < 4; ++j) {
                const int jj = s * 4 + j;
                pb.Wt[jj]  = wt + (size_t)j * WSQ;
                pb.Ab[jj]  = mx + (size_t)jj * NBT;
                pb.out[jj] = outs[j] + (size_t)s * NBT;
                pb.mu[jj]  = mu;                 // unused (mixA=0)
                pb.act[jj] = (j == 3) ? 1 : 0;
                pb.dirv[jj] = s;
            }
        }
        gemm_mfma_big<<<dim3(BT / 128, CC / 128, 8), 256, 0, stream>>>(
            pb, xbb, CC, CC, 0);

        lora1_kernel<<<dim3(BT / 16, 2), 256, 0, stream>>>(x, mu, dw1, lora, 0);
        gemm_kernel<<<dim3(BT / 64, CC / 64, 2), 256, 0, stream>>>(
            lora, dw2, wbias, wwbuf, 0);

        launch_scans(2, 0);   // scanA clobbers mx (aliased) AFTER gemm read it

        GB po = {};
        for (int s = 0; s < 2; ++s) {
            po.Wt[s]  = wtb + (size_t)s * 5 * WSQ + (size_t)4 * WSQ;
            po.Ab[s]  = zb + (size_t)s * NBT;
            po.out[s] = (s == 0) ? out : obuf;
            po.mu[s]  = mu;
            po.act[s] = 4;
            po.dirv[s] = s;
        }
        gemm_mfma_big<<<dim3(BT / 128, CC / 128, 2), 256, 0, stream>>>(
            po, xbb, CC, CC, 0);
    } else {
        // ---------- sequential fallback ----------
        for (int d = 0; d < 2; ++d) {
            const u16* wt = wtb + (size_t)d * 5 * WSQ;
            GB pb;
            float* outs[4] = {rbuf, kbuf, vbuf, gbuf};
            for (int j = 0; j < 4; ++j) {
                pb.Wt[j]  = wt + (size_t)j * WSQ;
                pb.Ab[j]  = mx + (size_t)j * NBT;
                pb.out[j] = outs[j];
                pb.mu[j]  = mu + (size_t)d * 5 * CC + (size_t)((j == 3) ? 4 : j) * CC;
                pb.act[j] = (j == 3) ? 1 : 0;
                pb.dirv[j] = d;
            }
            if (mixbuf) {
                mix4_kernel<<<dim3((int)(NBT / (8 * 256)), 4, 1), 256, 0, stream>>>(
                    xbb, muh, mx, d);
                gemm_mfma_big<<<dim3(BT / 128, CC / 128, 4), 256, 0, stream>>>(
                    pb, xbb, CC, CC, 0);
            } else {
                gemm_mfma_big<<<dim3(BT / 128, CC / 128, 4), 256, 0, stream>>>(
                    pb, xbb, CC, CC, 1);
            }
            lora1_kernel<<<dim3(BT / 16, 1), 256, 0, stream>>>(x, mu, dw1, lora, d);
            gemm_kernel<<<dim3(BT / 64, CC / 64, 1), 256, 0, stream>>>(
                lora, dw2, wbias, wwbuf, d);

            launch_scans(1, d);

            GB po = {};
            po.Wt[0]  = wt + (size_t)4 * WSQ;
            po.Ab[0]  = zb;
            po.out[0] = (d == 0) ? out : obuf;
            po.mu[0]  = mu;
            po.act[0] = 4;
            po.dirv[0] = d;
            gemm_mfma_big<<<dim3(BT / 128, CC / 128, 1), 256, 0, stream>>>(
                po, xbb, CC, CC, 0);
        }
    }

    combine_kernel<<<dim3((int)(NBT / (4 * 256))), 256, 0, stream>>>(
        out, obuf, mask);
}

// Round 18
// 328.605 us; speedup vs baseline: 1.0524x; 1.0524x over previous
//
#include <hip/hip_runtime.h>
#include <cstdint>
#include <cstddef>

// BiRWKV (RWKV-6 bidirectional time-mix), B=4 T=1024 C=768 H=12 D=64 LORA=64.
// Round 18: ladder prefers nch=32 (round-16 proven best: 328us; nch=64 doubled
// SL state traffic and scanB iterations -> net regression in round 17).
// scanC rebuilt as 2-wave d-split (128 thr): wave w owns S[32] for d in
// [32w,32w+32); halves per-wave FMAs and broadcast reads; wave1 ships its
// partial y via a double-buffered LDS line (1 barrier/step); wave0 does
// coef+GroupNorm+store. Everything else identical to rounds 16/17.

#define HH   12
#define DD   64
#define CC   768
#define TT   1024
#define BBB  4
#define LR   64
#define BT   (BBB*TT)
#define WSQ  (CC*CC)

typedef unsigned short u16;
typedef _Float16 f16x8 __attribute__((ext_vector_type(8)));  // 8 f16 (4 VGPRs)
typedef float f32x4 __attribute__((ext_vector_type(4)));     // MFMA accumulator

__device__ __forceinline__ u16 f2h(float f) {
    const _Float16 h = (_Float16)f;
    return __builtin_bit_cast(u16, h);
}
__device__ __forceinline__ float h2f(u16 h) {
    return (float)__builtin_bit_cast(_Float16, h);
}

// async global->LDS DMA, 16B per lane; LDS dest = wave-uniform base + lane*16.
__device__ __forceinline__ void gl_lds16(const void* g, void* l) {
    __builtin_amdgcn_global_load_lds(
        (const __attribute__((address_space(1))) void*)g,
        (__attribute__((address_space(3))) void*)l, 16, 0, 0);
}

// pad_mask dtype detect (bool bytes vs int32 vs float32).
__device__ __forceinline__ float mask_val(const void* mp, int idx) {
    const unsigned char* b = (const unsigned char*)mp;
    const int i0 = ((const int*)mp)[0];
    if (i0 == 0x3f800000) {
        return ((const float*)mp)[idx] != 0.f ? 1.f : 0.f;
    }
    if ((b[1] | b[2] | b[3]) == 0) {
        return ((const int*)mp)[idx] != 0 ? 1.f : 0.f;
    }
    return b[idx] ? 1.f : 0.f;
}

// ---------------- prepass: weight transpose-convert, x/mu convert -------------
struct TP10 { const float* src[10]; };

__global__ __launch_bounds__(256)
void transpose_conv(TP10 tj, u16* __restrict__ dst)
{
    __shared__ float sh[32][33];
    const int j = blockIdx.z;
    const float* __restrict__ src = tj.src[j];
    u16* __restrict__ d = dst + (size_t)j * WSQ;
    const int n0 = blockIdx.x << 5, k0 = blockIdx.y << 5;
    const int tx = threadIdx.x & 31, ty = threadIdx.x >> 5;
    #pragma unroll
    for (int i = 0; i < 4; ++i)
        sh[ty + (i << 3)][tx] = src[(size_t)(k0 + ty + (i << 3)) * CC + n0 + tx];
    __syncthreads();
    #pragma unroll
    for (int i = 0; i < 4; ++i)
        d[(size_t)(n0 + ty + (i << 3)) * CC + k0 + tx] =
            f2h(sh[tx][ty + (i << 3)]);
}

__global__ __launch_bounds__(256)
void convert_x(const float* __restrict__ x, u16* __restrict__ xb)
{
    const size_t off = ((size_t)blockIdx.x * 256 + threadIdx.x) * 8;
    const float4 a = *reinterpret_cast<const float4*>(x + off);
    const float4 b = *reinterpret_cast<const float4*>(x + off + 4);
    uint4 w;
    w.x = (unsigned)f2h(a.x) | ((unsigned)f2h(a.y) << 16);
    w.y = (unsigned)f2h(a.z) | ((unsigned)f2h(a.w) << 16);
    w.z = (unsigned)f2h(b.x) | ((unsigned)f2h(b.y) << 16);
    w.w = (unsigned)f2h(b.z) | ((unsigned)f2h(b.w) << 16);
    *reinterpret_cast<uint4*>(xb + off) = w;
}

__global__ __launch_bounds__(256)
void convert_mu(const float* __restrict__ mu, u16* __restrict__ muh, int n)
{
    const int i = blockIdx.x * 256 + threadIdx.x;
    if (i < n) muh[i] = f2h(mu[i]);
}

// ---------------- mix prepass: mixed fp16 A-buffers, both dirs ----------------
__global__ __launch_bounds__(256)
void mix4_kernel(const u16* __restrict__ xb, const u16* __restrict__ muh,
                 u16* __restrict__ mx, const int dbase)
{
    const int j = blockIdx.y;
    const int slot = blockIdx.z;
    const int dir = dbase + slot;
    const int idx = blockIdx.x * 256 + threadIdx.x;     // one uint4 (8 elems)
    const int s = idx / 96;                             // CC/8 = 96
    const int c = (idx - s * 96) << 3;
    const int b = s >> 10, ts = s & (TT - 1);
    const int t = dir ? (TT - 1 - ts) : ts;
    const int tp = dir ? (t + 1) : (t - 1);
    const int musel = (j == 3) ? 4 : j;

    const uint4 xa4 = *reinterpret_cast<const uint4*>(
        xb + (size_t)(b * TT + t) * CC + c);
    uint4 xp4 = make_uint4(0u, 0u, 0u, 0u);
    if (ts > 0)
        xp4 = *reinterpret_cast<const uint4*>(
            xb + (size_t)(b * TT + tp) * CC + c);
    const uint4 m4 = *reinterpret_cast<const uint4*>(
        muh + (size_t)dir * 5 * CC + musel * CC + c);

    const f16x8 xa = __builtin_bit_cast(f16x8, xa4);
    const f16x8 xp = __builtin_bit_cast(f16x8, xp4);
    const f16x8 mm = __builtin_bit_cast(f16x8, m4);
    const f16x8 res = (xp - xa) * mm + xa;              // v_pk_* fp16

    u16* __restrict__ dst = mx + (size_t)((slot << 2) + j) * ((size_t)BT * CC);
    *reinterpret_cast<uint4*>(dst + (size_t)s * CC + c) =
        __builtin_bit_cast(uint4, res);
}

// ---------------- fp16 MFMA GEMM: 128x128 tile, 4 waves, gl_lds staging -------
struct GB { const u16* Wt[8]; const u16* Ab[8]; float* out[8];
            const float* mu[8]; int act[8]; int dirv[8]; };

__global__ __launch_bounds__(256)
void gemm_mfma_big(GB p, const u16* __restrict__ xb,
                   const int K, const int N, const int mixA)
{
    const int j = blockIdx.z;
    const u16* __restrict__ Wt = p.Wt[j];
    const u16* __restrict__ Ab = p.Ab[j];
    float* __restrict__ out = p.out[j];
    const float* __restrict__ mu = p.mu[j];
    const int act = p.act[j];
    const int dir = p.dirv[j];

    __shared__ __align__(16) u16 Als[128][64];
    __shared__ __align__(16) u16 Bls[128][64];
    const int tid = threadIdx.x;
    const int rowbase = blockIdx.x << 7;
    const int colbase = blockIdx.y << 7;
    const int lane = tid & 63;
    const int wid = tid >> 6;           // 0..3
    const int wr = (wid >> 1) << 6;     // 0 / 64
    const int wc = (wid & 1) << 6;      // 0 / 64
    const int lm = lane & 15;

    const int lrow = lane >> 3;
    const int gcol = (((lane & 7) ^ lrow) << 3);

    f32x4 acc[4][4] = {};

    for (int k0 = 0; k0 < K; k0 += 64) {
        if (mixA) {
            #pragma unroll
            for (int it = 0; it < 4; ++it) {
                const int c   = tid + (it << 8);
                const int row = c >> 3;
                const int ch  = c & 7;
                const int kq  = (ch ^ (row & 7)) << 3;
                *reinterpret_cast<uint4*>(&Bls[row][ch << 3]) =
                    *reinterpret_cast<const uint4*>(
                        Wt + (size_t)(colbase + row) * K + k0 + kq);
                const int s  = rowbase + row;
                const int bb = s >> 10, ts = s & (TT - 1);
                const int t  = dir ? (TT - 1 - ts) : ts;
                const int tp = dir ? (t + 1) : (t - 1);
                const uint4 xa4 = *reinterpret_cast<const uint4*>(
                    xb + (size_t)(bb * TT + t) * CC + k0 + kq);
                uint4 xp4 = make_uint4(0u, 0u, 0u, 0u);
                if (ts > 0)
                    xp4 = *reinterpret_cast<const uint4*>(
                        xb + (size_t)(bb * TT + tp) * CC + k0 + kq);
                const u16* as = reinterpret_cast<const u16*>(&xa4);
                const u16* ps = reinterpret_cast<const u16*>(&xp4);
                const float4 m0 = *reinterpret_cast<const float4*>(mu + k0 + kq);
                const float4 m1 = *reinterpret_cast<const float4*>(mu + k0 + kq + 4);
                const float mm[8] = {m0.x, m0.y, m0.z, m0.w,
                                     m1.x, m1.y, m1.z, m1.w};
                uint4 w;
                unsigned rr[4];
                #pragma unroll
                for (int q = 0; q < 4; ++q) {
                    const float a0 = h2f(as[2 * q]);
                    const float a1 = h2f(as[2 * q + 1]);
                    const float p0 = h2f(ps[2 * q]);
                    const float p1 = h2f(ps[2 * q + 1]);
                    const float v0 = fmaf(p0 - a0, mm[2 * q], a0);
                    const float v1 = fmaf(p1 - a1, mm[2 * q + 1], a1);
                    rr[q] = (unsigned)f2h(v0) | ((unsigned)f2h(v1) << 16);
                }
                w.x = rr[0]; w.y = rr[1]; w.z = rr[2]; w.w = rr[3];
                *reinterpret_cast<uint4*>(&Als[row][ch << 3]) = w;
            }
        } else {
            #pragma unroll
            for (int i = 0; i < 4; ++i) {
                const int rb  = (wid << 5) + (i << 3);    // 8 rows / instr
                const int row = rb + lrow;
                gl_lds16(Ab + (size_t)(rowbase + row) * K + k0 + gcol,
                         &Als[rb][0]);
                gl_lds16(Wt + (size_t)(colbase + row) * K + k0 + gcol,
                         &Bls[rb][0]);
            }
        }
        __syncthreads();   // drains vmcnt(0): gl_lds data landed
        #pragma unroll
        for (int ks = 0; ks < 2; ++ks) {
            const int gc = (ks << 2) + (lane >> 4);       // global chunk
            const int sl = (gc ^ (lm & 7)) << 3;          // swizzled col
            f16x8 av[4], bv[4];
            #pragma unroll
            for (int mi = 0; mi < 4; ++mi)
                av[mi] = *reinterpret_cast<const f16x8*>(
                    &Als[wr + mi * 16 + lm][sl]);
            #pragma unroll
            for (int ni = 0; ni < 4; ++ni)
                bv[ni] = *reinterpret_cast<const f16x8*>(
                    &Bls[wc + ni * 16 + lm][sl]);
            #pragma unroll
            for (int mi = 0; mi < 4; ++mi)
                #pragma unroll
                for (int ni = 0; ni < 4; ++ni)
                    acc[mi][ni] = __builtin_amdgcn_mfma_f32_16x16x32_f16(
                        av[mi], bv[ni], acc[mi][ni], 0, 0, 0);
        }
        __syncthreads();
    }

    #pragma unroll
    for (int mi = 0; mi < 4; ++mi) {
        #pragma unroll
        for (int r = 0; r < 4; ++r) {
            const int srow = rowbase + wr + mi * 16 + ((lane >> 4) << 2) + r;
            if (act <= 1) {
                #pragma unroll
                for (int ni = 0; ni < 4; ++ni) {
                    float v = acc[mi][ni][r];
                    if (act == 1) v = v / (1.f + expf(-v));
                    out[(size_t)srow * N + colbase + wc + ni * 16 + lm] = v;
                }
            } else {   // act==4: store at original time order
                const int b2  = srow >> 10;
                const int ts2 = srow & (TT - 1);
                const int t2  = dir ? (TT - 1 - ts2) : ts2;
                float* op = out + (size_t)(b2 * TT + t2) * CC + colbase + wc + lm;
                #pragma unroll
                for (int ni = 0; ni < 4; ++ni)
                    op[ni * 16] = acc[mi][ni][r];
            }
        }
    }
}

// ---------------- combine: out = (fwd + bwd) * mask ----------------
__global__ __launch_bounds__(256)
void combine_kernel(float* __restrict__ out, const float* __restrict__ obuf,
                    const void* __restrict__ mask)
{
    const size_t idx = ((size_t)blockIdx.x * 256 + threadIdx.x) * 4;
    const int row = (int)(idx / CC);
    const float mv = mask_val(mask, row);
    const float4 a = *reinterpret_cast<const float4*>(out + idx);
    const float4 b = *reinterpret_cast<const float4*>(obuf + idx);
    *reinterpret_cast<float4*>(out + idx) = make_float4(
        (a.x + b.x) * mv, (a.y + b.y) * mv, (a.z + b.z) * mv, (a.w + b.w) * mv);
}

// ---------------- fp32 lora1 (x-mix @ dw1, tanh), 16-row tiles ----------------
__global__ __launch_bounds__(256)
void lora1_kernel(const float* __restrict__ x, const float* __restrict__ mu,
                  const float* __restrict__ dw1, float* __restrict__ out,
                  const int dbase)
{
    __shared__ float As[16][68];
    __shared__ float Bs[64][68];
    const int tid = threadIdx.x;
    const int rowbase = blockIdx.x << 4;
    const int slot = blockIdx.y;
    const int dir = dbase + slot;
    const float* __restrict__ muD = mu + (size_t)dir * 5 * CC + 3 * CC;
    const float* __restrict__ dw1p = dw1 + (size_t)dir * CC * LR;
    float* __restrict__ outp = out + (size_t)slot * BT * LR;

    const int arow = tid >> 4;
    const int akq  = (tid & 15) << 2;
    const int s  = rowbase + arow;
    const int bb = s >> 10, ts = s & (TT - 1);
    const int t  = dir ? (TT - 1 - ts) : ts;
    const int tp = dir ? (t + 1) : (t - 1);

    const int c0 = tid & 63;
    const int r4 = tid >> 6;

    float acc[4] = {0.f, 0.f, 0.f, 0.f};

    for (int k0 = 0; k0 < CC; k0 += 64) {
        {
            const int c = k0 + akq;
            const float4 xa = *reinterpret_cast<const float4*>(
                x + (size_t)(bb * TT + t) * CC + c);
            float4 xp = make_float4(0.f, 0.f, 0.f, 0.f);
            if (ts > 0)
                xp = *reinterpret_cast<const float4*>(
                    x + (size_t)(bb * TT + tp) * CC + c);
            const float4 m4 = *reinterpret_cast<const float4*>(muD + c);
            float4 va;
            va.x = fmaf(xp.x - xa.x, m4.x, xa.x);
            va.y = fmaf(xp.y - xa.y, m4.y, xa.y);
            va.z = fmaf(xp.z - xa.z, m4.z, xa.z);
            va.w = fmaf(xp.w - xa.w, m4.w, xa.w);
            *reinterpret_cast<float4*>(&As[arow][akq]) = va;
        }
        #pragma unroll
        for (int it = 0; it < 4; ++it) {
            const int c2 = tid + (it << 8);
            const int brow = c2 >> 4, bcol = (c2 & 15) << 2;
            *reinterpret_cast<float4*>(&Bs[brow][bcol]) =
                *reinterpret_cast<const float4*>(
                    dw1p + (size_t)(k0 + brow) * LR + bcol);
        }
        __syncthreads();
        #pragma unroll
        for (int k4 = 0; k4 < 16; ++k4) {
            float bv[4];
            #pragma unroll
            for (int q = 0; q < 4; ++q) bv[q] = Bs[(k4 << 2) + q][c0];
            #pragma unroll
            for (int i = 0; i < 4; ++i) {
                const float4 a4 = *reinterpret_cast<const float4*>(
                    &As[r4 + (i << 2)][k4 << 2]);
                acc[i] = fmaf(a4.x, bv[0], acc[i]);
                acc[i] = fmaf(a4.y, bv[1], acc[i]);
                acc[i] = fmaf(a4.z, bv[2], acc[i]);
                acc[i] = fmaf(a4.w, bv[3], acc[i]);
            }
        }
        __syncthreads();
    }
    #pragma unroll
    for (int i = 0; i < 4; ++i)
        outp[(size_t)(rowbase + r4 + (i << 2)) * LR + c0] = tanhf(acc[i]);
}

// ---------------- fp32 GEMM (lora2: decay exp(-exp)), both dirs ---------------
__global__ __launch_bounds__(256)
void gemm_kernel(const float* __restrict__ lora, const float* __restrict__ dw2,
                 const float* __restrict__ wbias, float* __restrict__ wwbuf,
                 const int dbase)
{
    __shared__ float As[16][68];
    __shared__ float Bs[16][68];
    const int tid = threadIdx.x;
    const int rowbase = blockIdx.x << 6;
    const int colbase = blockIdx.y << 6;
    const int slot = blockIdx.z;
    const int dir = dbase + slot;
    const float* __restrict__ Ap = lora + (size_t)slot * BT * LR;
    const float* __restrict__ W  = dw2 + (size_t)dir * LR * CC;
    const float* __restrict__ bias = wbias + (size_t)dir * CC;
    float* __restrict__ out = wwbuf + (size_t)slot * BT * CC;

    const int ty = tid >> 4, tx = tid & 15;
    const int am = tid >> 2;
    const int aq = tid & 3;
    const int s  = rowbase + am;
    const int bk = tid >> 4;
    const int bn = (tid & 15) << 2;

    float acc[4][4];
    #pragma unroll
    for (int i = 0; i < 4; ++i)
        #pragma unroll
        for (int j = 0; j < 4; ++j) acc[i][j] = 0.f;

    for (int k0 = 0; k0 < LR; k0 += 16) {
        const float4 va = *reinterpret_cast<const float4*>(
            Ap + (size_t)s * LR + k0 + (aq << 2));
        const float4 vb = *reinterpret_cast<const float4*>(
            W + (size_t)(k0 + bk) * CC + colbase + bn);
        As[(aq << 2) + 0][am] = va.x;
        As[(aq << 2) + 1][am] = va.y;
        As[(aq << 2) + 2][am] = va.z;
        As[(aq << 2) + 3][am] = va.w;
        *reinterpret_cast<float4*>(&Bs[bk][bn]) = vb;
        __syncthreads();
        #pragma unroll
        for (int kk = 0; kk < 16; ++kk) {
            const float4 a  = *reinterpret_cast<const float4*>(&As[kk][ty << 2]);
            const float4 bv = *reinterpret_cast<const float4*>(&Bs[kk][tx << 2]);
            const float av[4]  = {a.x, a.y, a.z, a.w};
            const float bvv[4] = {bv.x, bv.y, bv.z, bv.w};
            #pragma unroll
            for (int i = 0; i < 4; ++i)
                #pragma unroll
                for (int j = 0; j < 4; ++j)
                    acc[i][j] = fmaf(av[i], bvv[j], acc[i][j]);
        }
        __syncthreads();
    }

    #pragma unroll
    for (int i = 0; i < 4; ++i) {
        const int srow = rowbase + (ty << 2) + i;
        const int ncol = colbase + (tx << 2);
        float v[4];
        #pragma unroll
        for (int j = 0; j < 4; ++j)
            v[j] = expf(-expf(acc[i][j] + bias[ncol + j]));
        *reinterpret_cast<float4*>(out + (size_t)srow * CC + ncol) =
            make_float4(v[0], v[1], v[2], v[3]);
    }
}

// ---------------- chunked scan (A/B/C), dir-slot aware ----------------
template<int L>
__global__ __launch_bounds__(64)
void scanA_kernel(const float* __restrict__ kbuf, const float* __restrict__ vbuf,
                  const float* __restrict__ wbuf,
                  float* __restrict__ SL, float* __restrict__ Pbuf)
{
    constexpr int NCHL = TT / L;
    constexpr size_t SLN = (size_t)NCHL * BBB * HH * DD * DD;
    constexpr size_t PN  = (size_t)NCHL * BBB * HH * DD;
    __shared__ float lk[L * DD], lw[L * DD], lv[L * DD];
    const int c = blockIdx.x, h = blockIdx.y;
    const int b = blockIdx.z & (BBB - 1);
    const int slot = blockIdx.z >> 2;
    const size_t boff = (size_t)slot * BT * CC;
    const int e = threadIdx.x;
    const int rowq = e >> 4;
    const int col  = (e & 15) << 2;

    const size_t gbase = boff + (size_t)(b * TT + c * L) * CC + h * DD;
    #pragma unroll
    for (int r4 = 0; r4 < L / 4; ++r4) {
        const int row = (r4 << 2) + rowq;
        const size_t ga = gbase + (size_t)row * CC + col;
        *reinterpret_cast<float4*>(&lk[row * DD + col]) =
            *reinterpret_cast<const float4*>(kbuf + ga);
        *reinterpret_cast<float4*>(&lw[row * DD + col]) =
            *reinterpret_cast<const float4*>(wbuf + ga);
        *reinterpret_cast<float4*>(&lv[row * DD + col]) =
            *reinterpret_cast<const float4*>(vbuf + ga);
    }
    __syncthreads();

    float S[DD];
    #pragma unroll
    for (int d = 0; d < DD; ++d) S[d] = 0.f;
    float P = 1.f;

    for (int t = 0; t < L; ++t) {
        const float ve = lv[t * DD + e];
        P *= lw[t * DD + e];
        #pragma unroll
        for (int d4 = 0; d4 < 16; ++d4) {
            const float4 k4 = *reinterpret_cast<const float4*>(&lk[t * DD + (d4 << 2)]);
            const float4 w4 = *reinterpret_cast<const float4*>(&lw[t * DD + (d4 << 2)]);
            S[(d4 << 2) + 0] = fmaf(w4.x, S[(d4 << 2) + 0], k4.x * ve);
            S[(d4 << 2) + 1] = fmaf(w4.y, S[(d4 << 2) + 1], k4.y * ve);
            S[(d4 << 2) + 2] = fmaf(w4.z, S[(d4 << 2) + 2], k4.z * ve);
            S[(d4 << 2) + 3] = fmaf(w4.w, S[(d4 << 2) + 3], k4.w * ve);
        }
    }

    float* slotp = SL + (size_t)slot * SLN
                 + (size_t)((c * BBB + b) * HH + h) * DD * DD;
    #pragma unroll
    for (int d = 0; d < DD; ++d) slotp[d * DD + e] = S[d];
    Pbuf[(size_t)slot * PN + (size_t)((c * BBB + b) * HH + h) * DD + e] = P;
}

// Pass B: sequential over chunks, depth-1 register prefetch.
__global__ __launch_bounds__(64)
void scanB_kernel(float* __restrict__ SL, const float* __restrict__ Pbuf,
                  const int nch)
{
    const int h = blockIdx.x, b = blockIdx.y;
    const int dg = blockIdx.z & 3;
    const int slot = blockIdx.z >> 2;
    const size_t SLN = (size_t)nch * BBB * HH * DD * DD;
    const size_t PN  = (size_t)nch * BBB * HH * DD;
    float* __restrict__ SLs = SL + (size_t)slot * SLN;
    const float* __restrict__ Ps = Pbuf + (size_t)slot * PN;
    const int e = threadIdx.x;
    const size_t doff = (size_t)dg * 16 * DD;

    float S[16];
    #pragma unroll
    for (int i = 0; i < 16; ++i) S[i] = 0.f;

    float sl[16], pp[16];
    {
        const float* s0 = SLs + (size_t)(b * HH + h) * DD * DD + doff;
        const float* p0 = Ps + (size_t)(b * HH + h) * DD + dg * 16;
        #pragma unroll
        for (int i = 0; i < 16; ++i) { sl[i] = s0[i * DD + e]; pp[i] = p0[i]; }
    }
    for (int c = 0; c < nch; ++c) {
        float sl2[16], pp2[16];
        if (c + 1 < nch) {
            const float* s1 = SLs + (size_t)(((c + 1) * BBB + b) * HH + h) * DD * DD + doff;
            const float* p1 = Ps + (size_t)(((c + 1) * BBB + b) * HH + h) * DD + dg * 16;
            #pragma unroll
            for (int i = 0; i < 16; ++i) { sl2[i] = s1[i * DD + e]; pp2[i] = p1[i]; }
        }
        float* sc = SLs + (size_t)((c * BBB + b) * HH + h) * DD * DD + doff;
        #pragma unroll
        for (int i = 0; i < 16; ++i) {
            S[i] = fmaf(pp[i], S[i], sl[i]);
            sc[i * DD + e] = S[i];
        }
        #pragma unroll
        for (int i = 0; i < 16; ++i) { sl[i] = sl2[i]; pp[i] = pp2[i]; }
    }
}

// Pass C: 2-wave d-split (128 thr). Wave w owns S[d in [32w,32w+32)].
// Wave1 ships partial y via double-buffered LDS (1 barrier/step); wave0 adds
// partials + coef*v, GroupNorm-shfl over lanes, stores z. r/k packed fp16.
template<int L>
__global__ __launch_bounds__(128)
void scanC_kernel(const float* __restrict__ rbuf, const float* __restrict__ kbuf,
                  const float* __restrict__ vbuf, const float* __restrict__ wbuf,
                  const float* __restrict__ gbuf, const float* __restrict__ SL,
                  const float* __restrict__ u, const float* __restrict__ lnw,
                  const float* __restrict__ lnb, u16* __restrict__ zb,
                  const int dbase)
{
    constexpr int NCHL = TT / L;
    constexpr size_t SLN = (size_t)NCHL * BBB * HH * DD * DD;
    __shared__ unsigned lrk[L * DD];            // lo = r fp16, hi = k fp16
    __shared__ float lw[L * DD];
    __shared__ float pys[2][DD];                // wave1 partial y, dbuf by t&1

    const int c = blockIdx.x, h = blockIdx.y;
    const int b = blockIdx.z & (BBB - 1);
    const int slot = blockIdx.z >> 2;
    const int dir = dbase + slot;
    const size_t boff = (size_t)slot * BT * CC;
    const int tid = threadIdx.x;
    const int e = tid & 63;
    const int w = tid >> 6;                     // 0 / 1
    const int db = w << 5;                      // d base: 0 / 32

    const size_t gbase = boff + (size_t)(b * TT + c * L) * CC + h * DD;
    // staging with 128 threads: 8 rows per iteration
    {
        const int rowq = tid >> 4;              // 0..7
        const int col  = (tid & 15) << 2;
        #pragma unroll
        for (int r8 = 0; r8 < L / 8; ++r8) {
            const int row = (r8 << 3) + rowq;
            const size_t ga = gbase + (size_t)row * CC + col;
            const float4 rv = *reinterpret_cast<const float4*>(rbuf + ga);
            const float4 kv = *reinterpret_cast<const float4*>(kbuf + ga);
            const float4 wv = *reinterpret_cast<const float4*>(wbuf + ga);
            *reinterpret_cast<float4*>(&lw[row * DD + col]) = wv;
            uint4 pk;
            pk.x = (unsigned)f2h(rv.x) | ((unsigned)f2h(kv.x) << 16);
            pk.y = (unsigned)f2h(rv.y) | ((unsigned)f2h(kv.y) << 16);
            pk.z = (unsigned)f2h(rv.z) | ((unsigned)f2h(kv.z) << 16);
            pk.w = (unsigned)f2h(rv.w) | ((unsigned)f2h(kv.w) << 16);
            *reinterpret_cast<uint4*>(&lrk[row * DD + col]) = pk;
        }
    }
    __syncthreads();

    const float ue = u[(size_t)(dir * HH + h) * DD + e];
    const float gw = lnw[dir * CC + h * DD + e];
    const float gb = lnb[dir * CC + h * DD + e];

    float S[32];
    if (c == 0) {
        #pragma unroll
        for (int i = 0; i < 32; ++i) S[i] = 0.f;
    } else {
        const float* slotp = SL + (size_t)slot * SLN
                           + (size_t)(((c - 1) * BBB + b) * HH + h) * DD * DD;
        #pragma unroll
        for (int i = 0; i < 32; ++i) S[i] = slotp[(db + i) * DD + e];
    }

    float ve = vbuf[gbase + e];
    float ge = (w == 0) ? gbuf[gbase + e] : 0.f;
    for (int t = 0; t < L; ++t) {
        float ve2 = 0.f, ge2 = 0.f;
        if (t + 1 < L) {
            ve2 = vbuf[gbase + (size_t)(t + 1) * CC + e];
            if (w == 0) ge2 = gbuf[gbase + (size_t)(t + 1) * CC + e];
        }
        // partial y over this wave's 32 d's + state update
        float y0 = 0.f, y1 = 0.f, y2 = 0.f, y3 = 0.f;
        #pragma unroll
        for (int d8 = 0; d8 < 8; ++d8) {
            const int dd = db + (d8 << 2);
            const uint4 rk4 = *reinterpret_cast<const uint4*>(&lrk[t * DD + dd]);
            const float4 w4 = *reinterpret_cast<const float4*>(&lw[t * DD + dd]);
            const float r0 = h2f((u16)(rk4.x & 0xffffu)), k0 = h2f((u16)(rk4.x >> 16));
            const float r1 = h2f((u16)(rk4.y & 0xffffu)), k1 = h2f((u16)(rk4.y >> 16));
            const float r2 = h2f((u16)(rk4.z & 0xffffu)), k2 = h2f((u16)(rk4.z >> 16));
            const float r3 = h2f((u16)(rk4.w & 0xffffu)), k3 = h2f((u16)(rk4.w >> 16));
            y0 = fmaf(r0, S[(d8 << 2) + 0], y0);
            y1 = fmaf(r1, S[(d8 << 2) + 1], y1);
            y2 = fmaf(r2, S[(d8 << 2) + 2], y2);
            y3 = fmaf(r3, S[(d8 << 2) + 3], y3);
            S[(d8 << 2) + 0] = fmaf(w4.x, S[(d8 << 2) + 0], k0 * ve);
            S[(d8 << 2) + 1] = fmaf(w4.y, S[(d8 << 2) + 1], k1 * ve);
            S[(d8 << 2) + 2] = fmaf(w4.z, S[(d8 << 2) + 2], k2 * ve);
            S[(d8 << 2) + 3] = fmaf(w4.w, S[(d8 << 2) + 3], k3 * ve);
        }
        const float yp = (y0 + y1) + (y2 + y3);
        if (w == 1) pys[t & 1][e] = yp;
        __syncthreads();
        if (w == 0) {
            // coef = sum over all 64 channels of r*u*k (lane-indexed)
            const unsigned rke = lrk[t * DD + e];
            float coef = h2f((u16)(rke & 0xffffu)) * ue * h2f((u16)(rke >> 16));
            #pragma unroll
            for (int off = 32; off > 0; off >>= 1) coef += __shfl_xor(coef, off);

            float y = yp + pys[t & 1][e] + coef * ve;
            float sum = y, sq = y * y;
            #pragma unroll
            for (int off = 32; off > 0; off >>= 1) {
                sum += __shfl_xor(sum, off);
                sq  += __shfl_xor(sq, off);
            }
            const float mean = sum * (1.f / 64.f);
            const float var  = fmaf(-mean, mean, sq * (1.f / 64.f));
            const float yn   = (y - mean) * rsqrtf(var + 1e-5f) * gw + gb;
            zb[gbase + (size_t)t * CC + e] = f2h(yn * ge);
        }
        ve = ve2;
        ge = ge2;
    }
}

extern "C" void kernel_launch(void* const* d_in, const int* in_sizes, int n_in,
                              void* d_out, int out_size, void* d_ws, size_t ws_size,
                              hipStream_t stream)
{
    const float* x     = (const float*)d_in[0];
    const void*  mask  = d_in[1];
    const float* mu    = (const float*)d_in[2];
    const float* wbias = (const float*)d_in[3];
    const float* dw1   = (const float*)d_in[4];
    const float* dw2   = (const float*)d_in[5];
    const float* u     = (const float*)d_in[6];
    const float* Wr    = (const float*)d_in[7];
    const float* Wk    = (const float*)d_in[8];
    const float* Wv    = (const float*)d_in[9];
    const float* Wg    = (const float*)d_in[10];
    const float* Wo    = (const float*)d_in[11];
    const float* lnw   = (const float*)d_in[12];
    const float* lnb   = (const float*)d_in[13];
    float* out = (float*)d_out;

    float* ws = (float*)d_ws;
    const size_t NBT = (size_t)BT * CC;
    const size_t MUN = 2 * 5 * CC;

    auto plan = [&](int nd, int nch, bool mb, bool& alias) -> size_t {
        const size_t SLN = (size_t)nch * BBB * HH * DD * DD;
        const size_t PN  = (size_t)nch * BBB * HH * DD;
        const size_t slp = (size_t)nd * (SLN + PN) * 4;          // bytes
        const size_t mxb = mb ? (size_t)4 * nd * NBT * 2 : 0;    // bytes
        alias = mb && slp >= mxb;
        return ((size_t)5 * nd * NBT + (size_t)nd * BT * LR) * 4
             + slp
             + ((size_t)nd * NBT + NBT + (size_t)10 * WSQ + MUN) * 2
             + (alias ? 0 : mxb);
    };
    // prefer nch=32 (round-16 proven best; 64 doubles state traffic)
    int nd = 1, nch = 16; bool mixbuf = false, alias = false;
    {
        bool a;
        if      (plan(2, 32, true, a) <= ws_size) { nd = 2; nch = 32; mixbuf = true; alias = a; }
        else if (plan(2, 16, true, a) <= ws_size) { nd = 2; nch = 16; mixbuf = true; alias = a; }
        else {
            nd = 1;
            mixbuf = plan(1, 16, true, a) <= ws_size;
            if (mixbuf) alias = a;
            nch = (plan(1, 32, mixbuf, a) <= ws_size) ? 32 : 16;
            bool a2; (void)plan(1, nch, mixbuf, a2); alias = mixbuf && a2;
        }
    }
    const size_t SLN = (size_t)nch * BBB * HH * DD * DD;
    const size_t PN  = (size_t)nch * BBB * HH * DD;

    float* rbuf  = ws;                          // nd*NBT
    float* kbuf  = rbuf  + (size_t)nd * NBT;
    float* vbuf  = kbuf  + (size_t)nd * NBT;
    float* wwbuf = vbuf  + (size_t)nd * NBT;
    float* gbuf  = wwbuf + (size_t)nd * NBT;
    float* lora  = gbuf  + (size_t)nd * NBT;    // nd*BT*LR
    float* SL    = lora  + (size_t)nd * BT * LR;
    float* Pbuf  = SL    + (size_t)nd * SLN;
    u16*   zb    = (u16*)(Pbuf + (size_t)nd * PN);   // nd*NBT
    u16*   xbb   = zb + (size_t)nd * NBT;
    u16*   wtb   = xbb + NBT;
    u16*   muh   = wtb + (size_t)10 * WSQ;
    u16*   mx    = alias ? (u16*)SL : (muh + MUN);
    float* obuf  = rbuf;                        // free after scanC

    TP10 tj;
    const float* Wlist[5] = {Wr, Wk, Wv, Wg, Wo};
    for (int dir = 0; dir < 2; ++dir)
        for (int i = 0; i < 5; ++i)
            tj.src[dir * 5 + i] = Wlist[i] + (size_t)dir * WSQ;
    transpose_conv<<<dim3(24, 24, 10), 256, 0, stream>>>(tj, wtb);
    convert_x<<<dim3((int)(NBT / (8 * 256))), 256, 0, stream>>>(x, xbb);
    convert_mu<<<dim3((int)((MUN + 255) / 256)), 256, 0, stream>>>(mu, muh, (int)MUN);

    auto launch_scans = [&](int ndl, int dbase) {
        if (nch == 32) {
            scanA_kernel<32><<<dim3(32, HH, BBB * ndl), dim3(64), 0, stream>>>(
                kbuf, vbuf, wwbuf, SL, Pbuf);
            scanB_kernel<<<dim3(HH, BBB, 4 * ndl), dim3(64), 0, stream>>>(SL, Pbuf, 32);
            scanC_kernel<32><<<dim3(32, HH, BBB * ndl), dim3(128), 0, stream>>>(
                rbuf, kbuf, vbuf, wwbuf, gbuf, SL, u, lnw, lnb, zb, dbase);
        } else {
            scanA_kernel<64><<<dim3(16, HH, BBB * ndl), dim3(64), 0, stream>>>(
                kbuf, vbuf, wwbuf, SL, Pbuf);
            scanB_kernel<<<dim3(HH, BBB, 4 * ndl), dim3(64), 0, stream>>>(SL, Pbuf, 16);
            scanC_kernel<64><<<dim3(16, HH, BBB * ndl), dim3(128), 0, stream>>>(
                rbuf, kbuf, vbuf, wwbuf, gbuf, SL, u, lnw, lnb, zb, dbase);
        }
    };

    if (nd == 2) {
        // ---------- dual-direction fused path ----------
        mix4_kernel<<<dim3((int)(NBT / (8 * 256)), 4, 2), 256, 0, stream>>>(
            xbb, muh, mx, 0);

        GB pb;
        float* outs[4] = {rbuf, kbuf, vbuf, gbuf};
        for (int s = 0; s < 2; ++s) {
            const u16* wt = wtb + (size_t)s * 5 * WSQ;
            for (int j = 0; j < 4; ++j) {
                const int jj = s * 4 + j;
                pb.Wt[jj]  = wt + (size_t)j * WSQ;
                pb.Ab[jj]  = mx + (size_t)jj * NBT;
                pb.out[jj] = outs[j] + (size_t)s * NBT;
                pb.mu[jj]  = mu;                 // unused (mixA=0)
                pb.act[jj] = (j == 3) ? 1 : 0;
                pb.dirv[jj] = s;
            }
        }
        gemm_mfma_big<<<dim3(BT / 128, CC / 128, 8), 256, 0, stream>>>(
            pb, xbb, CC, CC, 0);

        lora1_kernel<<<dim3(BT / 16, 2), 256, 0, stream>>>(x, mu, dw1, lora, 0);
        gemm_kernel<<<dim3(BT / 64, CC / 64, 2), 256, 0, stream>>>(
            lora, dw2, wbias, wwbuf, 0);

        launch_scans(2, 0);   // scanA clobbers mx (aliased) AFTER gemm read it

        GB po = {};
        for (int s = 0; s < 2; ++s) {
            po.Wt[s]  = wtb + (size_t)s * 5 * WSQ + (size_t)4 * WSQ;
            po.Ab[s]  = zb + (size_t)s * NBT;
            po.out[s] = (s == 0) ? out : obuf;
            po.mu[s]  = mu;
            po.act[s] = 4;
            po.dirv[s] = s;
        }
        gemm_mfma_big<<<dim3(BT / 128, CC / 128, 2), 256, 0, stream>>>(
            po, xbb, CC, CC, 0);
    } else {
        // ---------- sequential fallback ----------
        for (int d = 0; d < 2; ++d) {
            const u16* wt = wtb + (size_t)d * 5 * WSQ;
            GB pb;
            float* outs[4] = {rbuf, kbuf, vbuf, gbuf};
            for (int j = 0; j < 4; ++j) {
                pb.Wt[j]  = wt + (size_t)j * WSQ;
                pb.Ab[j]  = mx + (size_t)j * NBT;
                pb.out[j] = outs[j];
                pb.mu[j]  = mu + (size_t)d * 5 * CC + (size_t)((j == 3) ? 4 : j) * CC;
                pb.act[j] = (j == 3) ? 1 : 0;
                pb.dirv[j] = d;
            }
            if (mixbuf) {
                mix4_kernel<<<dim3((int)(NBT / (8 * 256)), 4, 1), 256, 0, stream>>>(
                    xbb, muh, mx, d);
                gemm_mfma_big<<<dim3(BT / 128, CC / 128, 4), 256, 0, stream>>>(
                    pb, xbb, CC, CC, 0);
            } else {
                gemm_mfma_big<<<dim3(BT / 128, CC / 128, 4), 256, 0, stream>>>(
                    pb, xbb, CC, CC, 1);
            }
            lora1_kernel<<<dim3(BT / 16, 1), 256, 0, stream>>>(x, mu, dw1, lora, d);
            gemm_kernel<<<dim3(BT / 64, CC / 64, 1), 256, 0, stream>>>(
                lora, dw2, wbias, wwbuf, d);

            launch_scans(1, d);

            GB po = {};
            po.Wt[0]  = wt + (size_t)4 * WSQ;
            po.Ab[0]  = zb;
            po.out[0] = (d == 0) ? out : obuf;
            po.mu[0]  = mu;
            po.act[0] = 4;
            po.dirv[0] = d;
            gemm_mfma_big<<<dim3(BT / 128, CC / 128, 1), 256, 0, stream>>>(
                po, xbb, CC, CC, 0);
        }
    }

    combine_kernel<<<dim3((int)(NBT / (4 * 256))), 256, 0, stream>>>(
        out, obuf, mask);
}

// Round 19
// 327.723 us; speedup vs baseline: 1.0552x; 1.0027x over previous
//
#include <hip/hip_runtime.h>
#include <cstdint>
#include <cstddef>

// BiRWKV (RWKV-6 bidirectional time-mix), B=4 T=1024 C=768 H=12 D=64 LORA=64.
// Round 19 (final consolidation): round-16 proven-best scanC (single-wave,
// fp16-packed r/k, in-loop coef+GroupNorm) + round-18 launcher (nch=32-first
// ladder with mx/SL overlay). r15 (deferred reduce), r17 (nch=64), r18
// (2-wave split) all failed to beat this 328us configuration.

#define HH   12
#define DD   64
#define CC   768
#define TT   1024
#define BBB  4
#define LR   64
#define BT   (BBB*TT)
#define WSQ  (CC*CC)

typedef unsigned short u16;
typedef _Float16 f16x8 __attribute__((ext_vector_type(8)));  // 8 f16 (4 VGPRs)
typedef float f32x4 __attribute__((ext_vector_type(4)));     // MFMA accumulator

__device__ __forceinline__ u16 f2h(float f) {
    const _Float16 h = (_Float16)f;
    return __builtin_bit_cast(u16, h);
}
__device__ __forceinline__ float h2f(u16 h) {
    return (float)__builtin_bit_cast(_Float16, h);
}

// async global->LDS DMA, 16B per lane; LDS dest = wave-uniform base + lane*16.
__device__ __forceinline__ void gl_lds16(const void* g, void* l) {
    __builtin_amdgcn_global_load_lds(
        (const __attribute__((address_space(1))) void*)g,
        (__attribute__((address_space(3))) void*)l, 16, 0, 0);
}

// pad_mask dtype detect (bool bytes vs int32 vs float32).
__device__ __forceinline__ float mask_val(const void* mp, int idx) {
    const unsigned char* b = (const unsigned char*)mp;
    const int i0 = ((const int*)mp)[0];
    if (i0 == 0x3f800000) {
        return ((const float*)mp)[idx] != 0.f ? 1.f : 0.f;
    }
    if ((b[1] | b[2] | b[3]) == 0) {
        return ((const int*)mp)[idx] != 0 ? 1.f : 0.f;
    }
    return b[idx] ? 1.f : 0.f;
}

// ---------------- prepass: weight transpose-convert, x/mu convert -------------
struct TP10 { const float* src[10]; };

__global__ __launch_bounds__(256)
void transpose_conv(TP10 tj, u16* __restrict__ dst)
{
    __shared__ float sh[32][33];
    const int j = blockIdx.z;
    const float* __restrict__ src = tj.src[j];
    u16* __restrict__ d = dst + (size_t)j * WSQ;
    const int n0 = blockIdx.x << 5, k0 = blockIdx.y << 5;
    const int tx = threadIdx.x & 31, ty = threadIdx.x >> 5;
    #pragma unroll
    for (int i = 0; i < 4; ++i)
        sh[ty + (i << 3)][tx] = src[(size_t)(k0 + ty + (i << 3)) * CC + n0 + tx];
    __syncthreads();
    #pragma unroll
    for (int i = 0; i < 4; ++i)
        d[(size_t)(n0 + ty + (i << 3)) * CC + k0 + tx] =
            f2h(sh[tx][ty + (i << 3)]);
}

__global__ __launch_bounds__(256)
void convert_x(const float* __restrict__ x, u16* __restrict__ xb)
{
    const size_t off = ((size_t)blockIdx.x * 256 + threadIdx.x) * 8;
    const float4 a = *reinterpret_cast<const float4*>(x + off);
    const float4 b = *reinterpret_cast<const float4*>(x + off + 4);
    uint4 w;
    w.x = (unsigned)f2h(a.x) | ((unsigned)f2h(a.y) << 16);
    w.y = (unsigned)f2h(a.z) | ((unsigned)f2h(a.w) << 16);
    w.z = (unsigned)f2h(b.x) | ((unsigned)f2h(b.y) << 16);
    w.w = (unsigned)f2h(b.z) | ((unsigned)f2h(b.w) << 16);
    *reinterpret_cast<uint4*>(xb + off) = w;
}

__global__ __launch_bounds__(256)
void convert_mu(const float* __restrict__ mu, u16* __restrict__ muh, int n)
{
    const int i = blockIdx.x * 256 + threadIdx.x;
    if (i < n) muh[i] = f2h(mu[i]);
}

// ---------------- mix prepass: mixed fp16 A-buffers, both dirs ----------------
__global__ __launch_bounds__(256)
void mix4_kernel(const u16* __restrict__ xb, const u16* __restrict__ muh,
                 u16* __restrict__ mx, const int dbase)
{
    const int j = blockIdx.y;
    const int slot = blockIdx.z;
    const int dir = dbase + slot;
    const int idx = blockIdx.x * 256 + threadIdx.x;     // one uint4 (8 elems)
    const int s = idx / 96;                             // CC/8 = 96
    const int c = (idx - s * 96) << 3;
    const int b = s >> 10, ts = s & (TT - 1);
    const int t = dir ? (TT - 1 - ts) : ts;
    const int tp = dir ? (t + 1) : (t - 1);
    const int musel = (j == 3) ? 4 : j;

    const uint4 xa4 = *reinterpret_cast<const uint4*>(
        xb + (size_t)(b * TT + t) * CC + c);
    uint4 xp4 = make_uint4(0u, 0u, 0u, 0u);
    if (ts > 0)
        xp4 = *reinterpret_cast<const uint4*>(
            xb + (size_t)(b * TT + tp) * CC + c);
    const uint4 m4 = *reinterpret_cast<const uint4*>(
        muh + (size_t)dir * 5 * CC + musel * CC + c);

    const f16x8 xa = __builtin_bit_cast(f16x8, xa4);
    const f16x8 xp = __builtin_bit_cast(f16x8, xp4);
    const f16x8 mm = __builtin_bit_cast(f16x8, m4);
    const f16x8 res = (xp - xa) * mm + xa;              // v_pk_* fp16

    u16* __restrict__ dst = mx + (size_t)((slot << 2) + j) * ((size_t)BT * CC);
    *reinterpret_cast<uint4*>(dst + (size_t)s * CC + c) =
        __builtin_bit_cast(uint4, res);
}

// ---------------- fp16 MFMA GEMM: 128x128 tile, 4 waves, gl_lds staging -------
struct GB { const u16* Wt[8]; const u16* Ab[8]; float* out[8];
            const float* mu[8]; int act[8]; int dirv[8]; };

__global__ __launch_bounds__(256)
void gemm_mfma_big(GB p, const u16* __restrict__ xb,
                   const int K, const int N, const int mixA)
{
    const int j = blockIdx.z;
    const u16* __restrict__ Wt = p.Wt[j];
    const u16* __restrict__ Ab = p.Ab[j];
    float* __restrict__ out = p.out[j];
    const float* __restrict__ mu = p.mu[j];
    const int act = p.act[j];
    const int dir = p.dirv[j];

    __shared__ __align__(16) u16 Als[128][64];
    __shared__ __align__(16) u16 Bls[128][64];
    const int tid = threadIdx.x;
    const int rowbase = blockIdx.x << 7;
    const int colbase = blockIdx.y << 7;
    const int lane = tid & 63;
    const int wid = tid >> 6;           // 0..3
    const int wr = (wid >> 1) << 6;     // 0 / 64
    const int wc = (wid & 1) << 6;      // 0 / 64
    const int lm = lane & 15;

    const int lrow = lane >> 3;
    const int gcol = (((lane & 7) ^ lrow) << 3);

    f32x4 acc[4][4] = {};

    for (int k0 = 0; k0 < K; k0 += 64) {
        if (mixA) {
            #pragma unroll
            for (int it = 0; it < 4; ++it) {
                const int c   = tid + (it << 8);
                const int row = c >> 3;
                const int ch  = c & 7;
                const int kq  = (ch ^ (row & 7)) << 3;
                *reinterpret_cast<uint4*>(&Bls[row][ch << 3]) =
                    *reinterpret_cast<const uint4*>(
                        Wt + (size_t)(colbase + row) * K + k0 + kq);
                const int s  = rowbase + row;
                const int bb = s >> 10, ts = s & (TT - 1);
                const int t  = dir ? (TT - 1 - ts) : ts;
                const int tp = dir ? (t + 1) : (t - 1);
                const uint4 xa4 = *reinterpret_cast<const uint4*>(
                    xb + (size_t)(bb * TT + t) * CC + k0 + kq);
                uint4 xp4 = make_uint4(0u, 0u, 0u, 0u);
                if (ts > 0)
                    xp4 = *reinterpret_cast<const uint4*>(
                        xb + (size_t)(bb * TT + tp) * CC + k0 + kq);
                const u16* as = reinterpret_cast<const u16*>(&xa4);
                const u16* ps = reinterpret_cast<const u16*>(&xp4);
                const float4 m0 = *reinterpret_cast<const float4*>(mu + k0 + kq);
                const float4 m1 = *reinterpret_cast<const float4*>(mu + k0 + kq + 4);
                const float mm[8] = {m0.x, m0.y, m0.z, m0.w,
                                     m1.x, m1.y, m1.z, m1.w};
                uint4 w;
                unsigned rr[4];
                #pragma unroll
                for (int q = 0; q < 4; ++q) {
                    const float a0 = h2f(as[2 * q]);
                    const float a1 = h2f(as[2 * q + 1]);
                    const float p0 = h2f(ps[2 * q]);
                    const float p1 = h2f(ps[2 * q + 1]);
                    const float v0 = fmaf(p0 - a0, mm[2 * q], a0);
                    const float v1 = fmaf(p1 - a1, mm[2 * q + 1], a1);
                    rr[q] = (unsigned)f2h(v0) | ((unsigned)f2h(v1) << 16);
                }
                w.x = rr[0]; w.y = rr[1]; w.z = rr[2]; w.w = rr[3];
                *reinterpret_cast<uint4*>(&Als[row][ch << 3]) = w;
            }
        } else {
            #pragma unroll
            for (int i = 0; i < 4; ++i) {
                const int rb  = (wid << 5) + (i << 3);    // 8 rows / instr
                const int row = rb + lrow;
                gl_lds16(Ab + (size_t)(rowbase + row) * K + k0 + gcol,
                         &Als[rb][0]);
                gl_lds16(Wt + (size_t)(colbase + row) * K + k0 + gcol,
                         &Bls[rb][0]);
            }
        }
        __syncthreads();   // drains vmcnt(0): gl_lds data landed
        #pragma unroll
        for (int ks = 0; ks < 2; ++ks) {
            const int gc = (ks << 2) + (lane >> 4);       // global chunk
            const int sl = (gc ^ (lm & 7)) << 3;          // swizzled col
            f16x8 av[4], bv[4];
            #pragma unroll
            for (int mi = 0; mi < 4; ++mi)
                av[mi] = *reinterpret_cast<const f16x8*>(
                    &Als[wr + mi * 16 + lm][sl]);
            #pragma unroll
            for (int ni = 0; ni < 4; ++ni)
                bv[ni] = *reinterpret_cast<const f16x8*>(
                    &Bls[wc + ni * 16 + lm][sl]);
            #pragma unroll
            for (int mi = 0; mi < 4; ++mi)
                #pragma unroll
                for (int ni = 0; ni < 4; ++ni)
                    acc[mi][ni] = __builtin_amdgcn_mfma_f32_16x16x32_f16(
                        av[mi], bv[ni], acc[mi][ni], 0, 0, 0);
        }
        __syncthreads();
    }

    #pragma unroll
    for (int mi = 0; mi < 4; ++mi) {
        #pragma unroll
        for (int r = 0; r < 4; ++r) {
            const int srow = rowbase + wr + mi * 16 + ((lane >> 4) << 2) + r;
            if (act <= 1) {
                #pragma unroll
                for (int ni = 0; ni < 4; ++ni) {
                    float v = acc[mi][ni][r];
                    if (act == 1) v = v / (1.f + expf(-v));
                    out[(size_t)srow * N + colbase + wc + ni * 16 + lm] = v;
                }
            } else {   // act==4: store at original time order
                const int b2  = srow >> 10;
                const int ts2 = srow & (TT - 1);
                const int t2  = dir ? (TT - 1 - ts2) : ts2;
                float* op = out + (size_t)(b2 * TT + t2) * CC + colbase + wc + lm;
                #pragma unroll
                for (int ni = 0; ni < 4; ++ni)
                    op[ni * 16] = acc[mi][ni][r];
            }
        }
    }
}

// ---------------- combine: out = (fwd + bwd) * mask ----------------
__global__ __launch_bounds__(256)
void combine_kernel(float* __restrict__ out, const float* __restrict__ obuf,
                    const void* __restrict__ mask)
{
    const size_t idx = ((size_t)blockIdx.x * 256 + threadIdx.x) * 4;
    const int row = (int)(idx / CC);
    const float mv = mask_val(mask, row);
    const float4 a = *reinterpret_cast<const float4*>(out + idx);
    const float4 b = *reinterpret_cast<const float4*>(obuf + idx);
    *reinterpret_cast<float4*>(out + idx) = make_float4(
        (a.x + b.x) * mv, (a.y + b.y) * mv, (a.z + b.z) * mv, (a.w + b.w) * mv);
}

// ---------------- fp32 lora1 (x-mix @ dw1, tanh), 16-row tiles ----------------
__global__ __launch_bounds__(256)
void lora1_kernel(const float* __restrict__ x, const float* __restrict__ mu,
                  const float* __restrict__ dw1, float* __restrict__ out,
                  const int dbase)
{
    __shared__ float As[16][68];
    __shared__ float Bs[64][68];
    const int tid = threadIdx.x;
    const int rowbase = blockIdx.x << 4;
    const int slot = blockIdx.y;
    const int dir = dbase + slot;
    const float* __restrict__ muD = mu + (size_t)dir * 5 * CC + 3 * CC;
    const float* __restrict__ dw1p = dw1 + (size_t)dir * CC * LR;
    float* __restrict__ outp = out + (size_t)slot * BT * LR;

    const int arow = tid >> 4;
    const int akq  = (tid & 15) << 2;
    const int s  = rowbase + arow;
    const int bb = s >> 10, ts = s & (TT - 1);
    const int t  = dir ? (TT - 1 - ts) : ts;
    const int tp = dir ? (t + 1) : (t - 1);

    const int c0 = tid & 63;
    const int r4 = tid >> 6;

    float acc[4] = {0.f, 0.f, 0.f, 0.f};

    for (int k0 = 0; k0 < CC; k0 += 64) {
        {
            const int c = k0 + akq;
            const float4 xa = *reinterpret_cast<const float4*>(
                x + (size_t)(bb * TT + t) * CC + c);
            float4 xp = make_float4(0.f, 0.f, 0.f, 0.f);
            if (ts > 0)
                xp = *reinterpret_cast<const float4*>(
                    x + (size_t)(bb * TT + tp) * CC + c);
            const float4 m4 = *reinterpret_cast<const float4*>(muD + c);
            float4 va;
            va.x = fmaf(xp.x - xa.x, m4.x, xa.x);
            va.y = fmaf(xp.y - xa.y, m4.y, xa.y);
            va.z = fmaf(xp.z - xa.z, m4.z, xa.z);
            va.w = fmaf(xp.w - xa.w, m4.w, xa.w);
            *reinterpret_cast<float4*>(&As[arow][akq]) = va;
        }
        #pragma unroll
        for (int it = 0; it < 4; ++it) {
            const int c2 = tid + (it << 8);
            const int brow = c2 >> 4, bcol = (c2 & 15) << 2;
            *reinterpret_cast<float4*>(&Bs[brow][bcol]) =
                *reinterpret_cast<const float4*>(
                    dw1p + (size_t)(k0 + brow) * LR + bcol);
        }
        __syncthreads();
        #pragma unroll
        for (int k4 = 0; k4 < 16; ++k4) {
            float bv[4];
            #pragma unroll
            for (int q = 0; q < 4; ++q) bv[q] = Bs[(k4 << 2) + q][c0];
            #pragma unroll
            for (int i = 0; i < 4; ++i) {
                const float4 a4 = *reinterpret_cast<const float4*>(
                    &As[r4 + (i << 2)][k4 << 2]);
                acc[i] = fmaf(a4.x, bv[0], acc[i]);
                acc[i] = fmaf(a4.y, bv[1], acc[i]);
                acc[i] = fmaf(a4.z, bv[2], acc[i]);
                acc[i] = fmaf(a4.w, bv[3], acc[i]);
            }
        }
        __syncthreads();
    }
    #pragma unroll
    for (int i = 0; i < 4; ++i)
        outp[(size_t)(rowbase + r4 + (i << 2)) * LR + c0] = tanhf(acc[i]);
}

// ---------------- fp32 GEMM (lora2: decay exp(-exp)), both dirs ---------------
__global__ __launch_bounds__(256)
void gemm_kernel(const float* __restrict__ lora, const float* __restrict__ dw2,
                 const float* __restrict__ wbias, float* __restrict__ wwbuf,
                 const int dbase)
{
    __shared__ float As[16][68];
    __shared__ float Bs[16][68];
    const int tid = threadIdx.x;
    const int rowbase = blockIdx.x << 6;
    const int colbase = blockIdx.y << 6;
    const int slot = blockIdx.z;
    const int dir = dbase + slot;
    const float* __restrict__ Ap = lora + (size_t)slot * BT * LR;
    const float* __restrict__ W  = dw2 + (size_t)dir * LR * CC;
    const float* __restrict__ bias = wbias + (size_t)dir * CC;
    float* __restrict__ out = wwbuf + (size_t)slot * BT * CC;

    const int ty = tid >> 4, tx = tid & 15;
    const int am = tid >> 2;
    const int aq = tid & 3;
    const int s  = rowbase + am;
    const int bk = tid >> 4;
    const int bn = (tid & 15) << 2;

    float acc[4][4];
    #pragma unroll
    for (int i = 0; i < 4; ++i)
        #pragma unroll
        for (int j = 0; j < 4; ++j) acc[i][j] = 0.f;

    for (int k0 = 0; k0 < LR; k0 += 16) {
        const float4 va = *reinterpret_cast<const float4*>(
            Ap + (size_t)s * LR + k0 + (aq << 2));
        const float4 vb = *reinterpret_cast<const float4*>(
            W + (size_t)(k0 + bk) * CC + colbase + bn);
        As[(aq << 2) + 0][am] = va.x;
        As[(aq << 2) + 1][am] = va.y;
        As[(aq << 2) + 2][am] = va.z;
        As[(aq << 2) + 3][am] = va.w;
        *reinterpret_cast<float4*>(&Bs[bk][bn]) = vb;
        __syncthreads();
        #pragma unroll
        for (int kk = 0; kk < 16; ++kk) {
            const float4 a  = *reinterpret_cast<const float4*>(&As[kk][ty << 2]);
            const float4 bv = *reinterpret_cast<const float4*>(&Bs[kk][tx << 2]);
            const float av[4]  = {a.x, a.y, a.z, a.w};
            const float bvv[4] = {bv.x, bv.y, bv.z, bv.w};
            #pragma unroll
            for (int i = 0; i < 4; ++i)
                #pragma unroll
                for (int j = 0; j < 4; ++j)
                    acc[i][j] = fmaf(av[i], bvv[j], acc[i][j]);
        }
        __syncthreads();
    }

    #pragma unroll
    for (int i = 0; i < 4; ++i) {
        const int srow = rowbase + (ty << 2) + i;
        const int ncol = colbase + (tx << 2);
        float v[4];
        #pragma unroll
        for (int j = 0; j < 4; ++j)
            v[j] = expf(-expf(acc[i][j] + bias[ncol + j]));
        *reinterpret_cast<float4*>(out + (size_t)srow * CC + ncol) =
            make_float4(v[0], v[1], v[2], v[3]);
    }
}

// ---------------- chunked scan (A/B/C), dir-slot aware ----------------
template<int L>
__global__ __launch_bounds__(64)
void scanA_kernel(const float* __restrict__ kbuf, const float* __restrict__ vbuf,
                  const float* __restrict__ wbuf,
                  float* __restrict__ SL, float* __restrict__ Pbuf)
{
    constexpr int NCHL = TT / L;
    constexpr size_t SLN = (size_t)NCHL * BBB * HH * DD * DD;
    constexpr size_t PN  = (size_t)NCHL * BBB * HH * DD;
    __shared__ float lk[L * DD], lw[L * DD], lv[L * DD];
    const int c = blockIdx.x, h = blockIdx.y;
    const int b = blockIdx.z & (BBB - 1);
    const int slot = blockIdx.z >> 2;
    const size_t boff = (size_t)slot * BT * CC;
    const int e = threadIdx.x;
    const int rowq = e >> 4;
    const int col  = (e & 15) << 2;

    const size_t gbase = boff + (size_t)(b * TT + c * L) * CC + h * DD;
    #pragma unroll
    for (int r4 = 0; r4 < L / 4; ++r4) {
        const int row = (r4 << 2) + rowq;
        const size_t ga = gbase + (size_t)row * CC + col;
        *reinterpret_cast<float4*>(&lk[row * DD + col]) =
            *reinterpret_cast<const float4*>(kbuf + ga);
        *reinterpret_cast<float4*>(&lw[row * DD + col]) =
            *reinterpret_cast<const float4*>(wbuf + ga);
        *reinterpret_cast<float4*>(&lv[row * DD + col]) =
            *reinterpret_cast<const float4*>(vbuf + ga);
    }
    __syncthreads();

    float S[DD];
    #pragma unroll
    for (int d = 0; d < DD; ++d) S[d] = 0.f;
    float P = 1.f;

    for (int t = 0; t < L; ++t) {
        const float ve = lv[t * DD + e];
        P *= lw[t * DD + e];
        #pragma unroll
        for (int d4 = 0; d4 < 16; ++d4) {
            const float4 k4 = *reinterpret_cast<const float4*>(&lk[t * DD + (d4 << 2)]);
            const float4 w4 = *reinterpret_cast<const float4*>(&lw[t * DD + (d4 << 2)]);
            S[(d4 << 2) + 0] = fmaf(w4.x, S[(d4 << 2) + 0], k4.x * ve);
            S[(d4 << 2) + 1] = fmaf(w4.y, S[(d4 << 2) + 1], k4.y * ve);
            S[(d4 << 2) + 2] = fmaf(w4.z, S[(d4 << 2) + 2], k4.z * ve);
            S[(d4 << 2) + 3] = fmaf(w4.w, S[(d4 << 2) + 3], k4.w * ve);
        }
    }

    float* slotp = SL + (size_t)slot * SLN
                 + (size_t)((c * BBB + b) * HH + h) * DD * DD;
    #pragma unroll
    for (int d = 0; d < DD; ++d) slotp[d * DD + e] = S[d];
    Pbuf[(size_t)slot * PN + (size_t)((c * BBB + b) * HH + h) * DD + e] = P;
}

// Pass B: sequential over chunks, depth-1 register prefetch.
__global__ __launch_bounds__(64)
void scanB_kernel(float* __restrict__ SL, const float* __restrict__ Pbuf,
                  const int nch)
{
    const int h = blockIdx.x, b = blockIdx.y;
    const int dg = blockIdx.z & 3;
    const int slot = blockIdx.z >> 2;
    const size_t SLN = (size_t)nch * BBB * HH * DD * DD;
    const size_t PN  = (size_t)nch * BBB * HH * DD;
    float* __restrict__ SLs = SL + (size_t)slot * SLN;
    const float* __restrict__ Ps = Pbuf + (size_t)slot * PN;
    const int e = threadIdx.x;
    const size_t doff = (size_t)dg * 16 * DD;

    float S[16];
    #pragma unroll
    for (int i = 0; i < 16; ++i) S[i] = 0.f;

    float sl[16], pp[16];
    {
        const float* s0 = SLs + (size_t)(b * HH + h) * DD * DD + doff;
        const float* p0 = Ps + (size_t)(b * HH + h) * DD + dg * 16;
        #pragma unroll
        for (int i = 0; i < 16; ++i) { sl[i] = s0[i * DD + e]; pp[i] = p0[i]; }
    }
    for (int c = 0; c < nch; ++c) {
        float sl2[16], pp2[16];
        if (c + 1 < nch) {
            const float* s1 = SLs + (size_t)(((c + 1) * BBB + b) * HH + h) * DD * DD + doff;
            const float* p1 = Ps + (size_t)(((c + 1) * BBB + b) * HH + h) * DD + dg * 16;
            #pragma unroll
            for (int i = 0; i < 16; ++i) { sl2[i] = s1[i * DD + e]; pp2[i] = p1[i]; }
        }
        float* sc = SLs + (size_t)((c * BBB + b) * HH + h) * DD * DD + doff;
        #pragma unroll
        for (int i = 0; i < 16; ++i) {
            S[i] = fmaf(pp[i], S[i], sl[i]);
            sc[i * DD + e] = S[i];
        }
        #pragma unroll
        for (int i = 0; i < 16; ++i) { sl[i] = sl2[i]; pp[i] = pp2[i]; }
    }
}

// Pass C (round-16 proven form): single wave, in-loop coef+GroupNorm shfl,
// r/k packed fp16 in one LDS array (lo=r, hi=k). LDS 16.6 KB at L=32.
template<int L>
__global__ __launch_bounds__(64)
void scanC_kernel(const float* __restrict__ rbuf, const float* __restrict__ kbuf,
                  const float* __restrict__ vbuf, const float* __restrict__ wbuf,
                  const float* __restrict__ gbuf, const float* __restrict__ SL,
                  const float* __restrict__ u, const float* __restrict__ lnw,
                  const float* __restrict__ lnb, u16* __restrict__ zb,
                  const int dbase)
{
    constexpr int NCHL = TT / L;
    constexpr size_t SLN = (size_t)NCHL * BBB * HH * DD * DD;
    __shared__ unsigned lrk[L * DD];            // lo = r fp16, hi = k fp16
    __shared__ float lw[L * DD];

    const int c = blockIdx.x, h = blockIdx.y;
    const int b = blockIdx.z & (BBB - 1);
    const int slot = blockIdx.z >> 2;
    const int dir = dbase + slot;
    const size_t boff = (size_t)slot * BT * CC;
    const int e = threadIdx.x;
    const int rowq = e >> 4;
    const int col  = (e & 15) << 2;

    const size_t gbase = boff + (size_t)(b * TT + c * L) * CC + h * DD;
    #pragma unroll
    for (int r4 = 0; r4 < L / 4; ++r4) {
        const int row = (r4 << 2) + rowq;
        const size_t ga = gbase + (size_t)row * CC + col;
        const float4 rv = *reinterpret_cast<const float4*>(rbuf + ga);
        const float4 kv = *reinterpret_cast<const float4*>(kbuf + ga);
        const float4 wv = *reinterpret_cast<const float4*>(wbuf + ga);
        *reinterpret_cast<float4*>(&lw[row * DD + col]) = wv;
        uint4 pk;
        pk.x = (unsigned)f2h(rv.x) | ((unsigned)f2h(kv.x) << 16);
        pk.y = (unsigned)f2h(rv.y) | ((unsigned)f2h(kv.y) << 16);
        pk.z = (unsigned)f2h(rv.z) | ((unsigned)f2h(kv.z) << 16);
        pk.w = (unsigned)f2h(rv.w) | ((unsigned)f2h(kv.w) << 16);
        *reinterpret_cast<uint4*>(&lrk[row * DD + col]) = pk;
    }
    __syncthreads();

    const float ue = u[(size_t)(dir * HH + h) * DD + e];
    const float gw = lnw[dir * CC + h * DD + e];
    const float gb = lnb[dir * CC + h * DD + e];

    float S[DD];
    if (c == 0) {
        #pragma unroll
        for (int d = 0; d < DD; ++d) S[d] = 0.f;
    } else {
        const float* slotp = SL + (size_t)slot * SLN
                           + (size_t)(((c - 1) * BBB + b) * HH + h) * DD * DD;
        #pragma unroll
        for (int d = 0; d < DD; ++d) S[d] = slotp[d * DD + e];
    }

    float ve = vbuf[gbase + e];
    float ge = gbuf[gbase + e];
    for (int t = 0; t < L; ++t) {
        float ve2 = 0.f, ge2 = 0.f;
        if (t + 1 < L) {
            ve2 = vbuf[gbase + (size_t)(t + 1) * CC + e];
            ge2 = gbuf[gbase + (size_t)(t + 1) * CC + e];
        }
        const unsigned rke = lrk[t * DD + e];
        float coef = h2f((u16)(rke & 0xffffu)) * ue * h2f((u16)(rke >> 16));
        #pragma unroll
        for (int off = 32; off > 0; off >>= 1) coef += __shfl_xor(coef, off);

        float y0 = 0.f, y1 = 0.f, y2 = 0.f, y3 = 0.f;
        #pragma unroll
        for (int d4 = 0; d4 < 16; ++d4) {
            const uint4 rk4 = *reinterpret_cast<const uint4*>(
                &lrk[t * DD + (d4 << 2)]);
            const float4 w4 = *reinterpret_cast<const float4*>(
                &lw[t * DD + (d4 << 2)]);
            const float r0 = h2f((u16)(rk4.x & 0xffffu)), k0 = h2f((u16)(rk4.x >> 16));
            const float r1 = h2f((u16)(rk4.y & 0xffffu)), k1 = h2f((u16)(rk4.y >> 16));
            const float r2 = h2f((u16)(rk4.z & 0xffffu)), k2 = h2f((u16)(rk4.z >> 16));
            const float r3 = h2f((u16)(rk4.w & 0xffffu)), k3 = h2f((u16)(rk4.w >> 16));
            y0 = fmaf(r0, S[(d4 << 2) + 0], y0);
            y1 = fmaf(r1, S[(d4 << 2) + 1], y1);
            y2 = fmaf(r2, S[(d4 << 2) + 2], y2);
            y3 = fmaf(r3, S[(d4 << 2) + 3], y3);
            S[(d4 << 2) + 0] = fmaf(w4.x, S[(d4 << 2) + 0], k0 * ve);
            S[(d4 << 2) + 1] = fmaf(w4.y, S[(d4 << 2) + 1], k1 * ve);
            S[(d4 << 2) + 2] = fmaf(w4.z, S[(d4 << 2) + 2], k2 * ve);
            S[(d4 << 2) + 3] = fmaf(w4.w, S[(d4 << 2) + 3], k3 * ve);
        }
        float y = ((y0 + y1) + (y2 + y3)) + coef * ve;

        float sum = y, sq = y * y;
        #pragma unroll
        for (int off = 32; off > 0; off >>= 1) {
            sum += __shfl_xor(sum, off);
            sq  += __shfl_xor(sq, off);
        }
        const float mean = sum * (1.f / 64.f);
        const float var  = fmaf(-mean, mean, sq * (1.f / 64.f));
        const float yn   = (y - mean) * rsqrtf(var + 1e-5f) * gw + gb;
        zb[gbase + (size_t)t * CC + e] = f2h(yn * ge);
        ve = ve2;
        ge = ge2;
    }
}

extern "C" void kernel_launch(void* const* d_in, const int* in_sizes, int n_in,
                              void* d_out, int out_size, void* d_ws, size_t ws_size,
                              hipStream_t stream)
{
    const float* x     = (const float*)d_in[0];
    const void*  mask  = d_in[1];
    const float* mu    = (const float*)d_in[2];
    const float* wbias = (const float*)d_in[3];
    const float* dw1   = (const float*)d_in[4];
    const float* dw2   = (const float*)d_in[5];
    const float* u     = (const float*)d_in[6];
    const float* Wr    = (const float*)d_in[7];
    const float* Wk    = (const float*)d_in[8];
    const float* Wv    = (const float*)d_in[9];
    const float* Wg    = (const float*)d_in[10];
    const float* Wo    = (const float*)d_in[11];
    const float* lnw   = (const float*)d_in[12];
    const float* lnb   = (const float*)d_in[13];
    float* out = (float*)d_out;

    float* ws = (float*)d_ws;
    const size_t NBT = (size_t)BT * CC;
    const size_t MUN = 2 * 5 * CC;

    auto plan = [&](int nd, int nch, bool mb, bool& alias) -> size_t {
        const size_t SLN = (size_t)nch * BBB * HH * DD * DD;
        const size_t PN  = (size_t)nch * BBB * HH * DD;
        const size_t slp = (size_t)nd * (SLN + PN) * 4;          // bytes
        const size_t mxb = mb ? (size_t)4 * nd * NBT * 2 : 0;    // bytes
        alias = mb && slp >= mxb;
        return ((size_t)5 * nd * NBT + (size_t)nd * BT * LR) * 4
             + slp
             + ((size_t)nd * NBT + NBT + (size_t)10 * WSQ + MUN) * 2
             + (alias ? 0 : mxb);
    };
    // nch=32 preferred (proven best; 64 doubles state traffic)
    int nd = 1, nch = 16; bool mixbuf = false, alias = false;
    {
        bool a;
        if      (plan(2, 32, true, a) <= ws_size) { nd = 2; nch = 32; mixbuf = true; alias = a; }
        else if (plan(2, 16, true, a) <= ws_size) { nd = 2; nch = 16; mixbuf = true; alias = a; }
        else {
            nd = 1;
            mixbuf = plan(1, 16, true, a) <= ws_size;
            if (mixbuf) alias = a;
            nch = (plan(1, 32, mixbuf, a) <= ws_size) ? 32 : 16;
            bool a2; (void)plan(1, nch, mixbuf, a2); alias = mixbuf && a2;
        }
    }
    const size_t SLN = (size_t)nch * BBB * HH * DD * DD;
    const size_t PN  = (size_t)nch * BBB * HH * DD;

    float* rbuf  = ws;                          // nd*NBT
    float* kbuf  = rbuf  + (size_t)nd * NBT;
    float* vbuf  = kbuf  + (size_t)nd * NBT;
    float* wwbuf = vbuf  + (size_t)nd * NBT;
    float* gbuf  = wwbuf + (size_t)nd * NBT;
    float* lora  = gbuf  + (size_t)nd * NBT;    // nd*BT*LR
    float* SL    = lora  + (size_t)nd * BT * LR;
    float* Pbuf  = SL    + (size_t)nd * SLN;
    u16*   zb    = (u16*)(Pbuf + (size_t)nd * PN);   // nd*NBT
    u16*   xbb   = zb + (size_t)nd * NBT;
    u16*   wtb   = xbb + NBT;
    u16*   muh   = wtb + (size_t)10 * WSQ;
    u16*   mx    = alias ? (u16*)SL : (muh + MUN);
    float* obuf  = rbuf;                        // free after scanC

    TP10 tj;
    const float* Wlist[5] = {Wr, Wk, Wv, Wg, Wo};
    for (int dir = 0; dir < 2; ++dir)
        for (int i = 0; i < 5; ++i)
            tj.src[dir * 5 + i] = Wlist[i] + (size_t)dir * WSQ;
    transpose_conv<<<dim3(24, 24, 10), 256, 0, stream>>>(tj, wtb);
    convert_x<<<dim3((int)(NBT / (8 * 256))), 256, 0, stream>>>(x, xbb);
    convert_mu<<<dim3((int)((MUN + 255) / 256)), 256, 0, stream>>>(mu, muh, (int)MUN);

    auto launch_scans = [&](int ndl, int dbase) {
        if (nch == 32) {
            scanA_kernel<32><<<dim3(32, HH, BBB * ndl), dim3(64), 0, stream>>>(
                kbuf, vbuf, wwbuf, SL, Pbuf);
            scanB_kernel<<<dim3(HH, BBB, 4 * ndl), dim3(64), 0, stream>>>(SL, Pbuf, 32);
            scanC_kernel<32><<<dim3(32, HH, BBB * ndl), dim3(64), 0, stream>>>(
                rbuf, kbuf, vbuf, wwbuf, gbuf, SL, u, lnw, lnb, zb, dbase);
        } else {
            scanA_kernel<64><<<dim3(16, HH, BBB * ndl), dim3(64), 0, stream>>>(
                kbuf, vbuf, wwbuf, SL, Pbuf);
            scanB_kernel<<<dim3(HH, BBB, 4 * ndl), dim3(64), 0, stream>>>(SL, Pbuf, 16);
            scanC_kernel<64><<<dim3(16, HH, BBB * ndl), dim3(64), 0, stream>>>(
                rbuf, kbuf, vbuf, wwbuf, gbuf, SL, u, lnw, lnb, zb, dbase);
        }
    };

    if (nd == 2) {
        // ---------- dual-direction fused path ----------
        mix4_kernel<<<dim3((int)(NBT / (8 * 256)), 4, 2), 256, 0, stream>>>(
            xbb, muh, mx, 0);

        GB pb;
        float* outs[4] = {rbuf, kbuf, vbuf, gbuf};
        for (int s = 0; s < 2; ++s) {
            const u16* wt = wtb + (size_t)s * 5 * WSQ;
            for (int j = 0; j < 4; ++j) {
                const int jj = s * 4 + j;
                pb.Wt[jj]  = wt + (size_t)j * WSQ;
                pb.Ab[jj]  = mx + (size_t)jj * NBT;
                pb.out[jj] = outs[j] + (size_t)s * NBT;
                pb.mu[jj]  = mu;                 // unused (mixA=0)
                pb.act[jj] = (j == 3) ? 1 : 0;
                pb.dirv[jj] = s;
            }
        }
        gemm_mfma_big<<<dim3(BT / 128, CC / 128, 8), 256, 0, stream>>>(
            pb, xbb, CC, CC, 0);

        lora1_kernel<<<dim3(BT / 16, 2), 256, 0, stream>>>(x, mu, dw1, lora, 0);
        gemm_kernel<<<dim3(BT / 64, CC / 64, 2), 256, 0, stream>>>(
            lora, dw2, wbias, wwbuf, 0);

        launch_scans(2, 0);   // scanA clobbers mx (aliased) AFTER gemm read it

        GB po = {};
        for (int s = 0; s < 2; ++s) {
            po.Wt[s]  = wtb + (size_t)s * 5 * WSQ + (size_t)4 * WSQ;
            po.Ab[s]  = zb + (size_t)s * NBT;
            po.out[s] = (s == 0) ? out : obuf;
            po.mu[s]  = mu;
            po.act[s] = 4;
            po.dirv[s] = s;
        }
        gemm_mfma_big<<<dim3(BT / 128, CC / 128, 2), 256, 0, stream>>>(
            po, xbb, CC, CC, 0);
    } else {
        // ---------- sequential fallback ----------
        for (int d = 0; d < 2; ++d) {
            const u16* wt = wtb + (size_t)d * 5 * WSQ;
            GB pb;
            float* outs[4] = {rbuf, kbuf, vbuf, gbuf};
            for (int j = 0; j < 4; ++j) {
                pb.Wt[j]  = wt + (size_t)j * WSQ;
                pb.Ab[j]  = mx + (size_t)j * NBT;
                pb.out[j] = outs[j];
                pb.mu[j]  = mu + (size_t)d * 5 * CC + (size_t)((j == 3) ? 4 : j) * CC;
                pb.act[j] = (j == 3) ? 1 : 0;
                pb.dirv[j] = d;
            }
            if (mixbuf) {
                mix4_kernel<<<dim3((int)(NBT / (8 * 256)), 4, 1), 256, 0, stream>>>(
                    xbb, muh, mx, d);
                gemm_mfma_big<<<dim3(BT / 128, CC / 128, 4), 256, 0, stream>>>(
                    pb, xbb, CC, CC, 0);
            } else {
                gemm_mfma_big<<<dim3(BT / 128, CC / 128, 4), 256, 0, stream>>>(
                    pb, xbb, CC, CC, 1);
            }
            lora1_kernel<<<dim3(BT / 16, 1), 256, 0, stream>>>(x, mu, dw1, lora, d);
            gemm_kernel<<<dim3(BT / 64, CC / 64, 1), 256, 0, stream>>>(
                lora, dw2, wbias, wwbuf, d);

            launch_scans(1, d);

            GB po = {};
            po.Wt[0]  = wt + (size_t)4 * WSQ;
            po.Ab[0]  = zb;
            po.out[0] = (d == 0) ? out : obuf;
            po.mu[0]  = mu;
            po.act[0] = 4;
            po.dirv[0] = d;
            gemm_mfma_big<<<dim3(BT / 128, CC / 128, 1), 256, 0, stream>>>(
                po, xbb, CC, CC, 0);
        }
    }

    combine_kernel<<<dim3((int)(NBT / (4 * 256))), 256, 0, stream>>>(
        out, obuf, mask);
}